// Round 4
// baseline (4730.483 us; speedup 1.0000x reference)
//
#include <hip/hip_runtime.h>

typedef unsigned short u16;

#define DIM 2048

__device__ inline u16 f2bf(float f) {
    unsigned u = __builtin_bit_cast(unsigned, f);
    u = (u + 0x7FFFu + ((u >> 16) & 1u)) >> 16;   // RNE, finite inputs only
    return (u16)u;
}
__device__ inline float bf2f(u16 h) {
    return __builtin_bit_cast(float, (unsigned)h << 16);
}

struct c32 { float x, y; };
__device__ inline c32 cmul(c32 a, c32 b) { return {a.x*b.x - a.y*b.y, a.x*b.y + a.y*b.x}; }

// ---------------------------------------------------------------------------
// Kernel 1: build T = U^T (row j = column j of U) by per-column statevector
// simulation in LDS. Literal transcription of the reference: per layer, 11
// single-qubit fused gates, then (layers 0..3) the 11 ring CNOT permutations
// applied SEQUENTIALLY (U = U[p_c], c = 0..10) with ping-pong buffers.
// Grid: 2048 blocks x 256 threads.
// ---------------------------------------------------------------------------
__global__ __launch_bounds__(256) void build_ut(const float* __restrict__ w,
                                                u16* __restrict__ ut_re,
                                                u16* __restrict__ ut_im) {
    __shared__ alignas(16) float gre[55][4], gim[55][4];
    __shared__ alignas(16) float vr[2][DIM], vi[2][DIM];
    const int tid = threadIdx.x;
    const int col = blockIdx.x;

    if (tid < 55) {
        const int layer = tid / 11, q = tid - layer * 11;
        const float WM = 0.63245553203367586f;   // sqrt(2)*5^-0.5
        float hx = 0.5f * WM * w[33*layer + q];
        float hy = 0.5f * WM * w[33*layer + 11 + q];
        float hz = 0.5f * WM * w[33*layer + 22 + q];
        float cx = cosf(hx), sx = sinf(hx);
        float cy = cosf(hy), sy = sinf(hy);
        float cz = cosf(hz), sz = sinf(hz);
        // Ry*Rx
        c32 m00{cy*cx,  sy*sx}, m01{-sy*cx, -cy*sx};
        c32 m10{sy*cx, -cy*sx}, m11{ cy*cx, -sy*sx};
        c32 em{cz, -sz}, ep{cz, sz};             // e^{-i hz}, e^{+i hz}
        c32 r0 = cmul(em, m00), r1 = cmul(em, m01);
        c32 r2 = cmul(ep, m10), r3 = cmul(ep, m11);
        gre[tid][0] = r0.x; gim[tid][0] = r0.y;
        gre[tid][1] = r1.x; gim[tid][1] = r1.y;
        gre[tid][2] = r2.x; gim[tid][2] = r2.y;
        gre[tid][3] = r3.x; gim[tid][3] = r3.y;
    }
    for (int i = tid; i < DIM; i += 256) { vr[0][i] = (i == col) ? 1.0f : 0.0f; vi[0][i] = 0.0f; }
    __syncthreads();

    int cur = 0;
    for (int layer = 0; layer < 5; ++layer) {
        for (int q = 0; q < 11; ++q) {
            const int gi = layer*11 + q;
            const float g00r = gre[gi][0], g00i = gim[gi][0];
            const float g01r = gre[gi][1], g01i = gim[gi][1];
            const float g10r = gre[gi][2], g10i = gim[gi][2];
            const float g11r = gre[gi][3], g11i = gim[gi][3];
            const int s = 10 - q;   // MSB-first: qubit q -> bit (n-1-q)
            for (int p = tid; p < 1024; p += 256) {
                int i0 = ((p >> s) << (s + 1)) | (p & ((1 << s) - 1));
                int i1 = i0 | (1 << s);
                float ar = vr[cur][i0], ai = vi[cur][i0];
                float br = vr[cur][i1], bi = vi[cur][i1];
                vr[cur][i0] = g00r*ar - g00i*ai + g01r*br - g01i*bi;
                vi[cur][i0] = g00r*ai + g00i*ar + g01r*bi + g01i*br;
                vr[cur][i1] = g10r*ar - g10i*ai + g11r*br - g11i*bi;
                vi[cur][i1] = g10r*ai + g10i*ar + g11r*bi + g11i*br;
            }
            __syncthreads();
        }
        if (layer < 4) {
            // U = U[p_c] sequentially, c = 0..10 (reference order).
            // Column view: v_new[i] = v_old[p_c(i)].
            for (int c = 0; c < 11; ++c) {
                const int nxt = cur ^ 1;
                const int sc = 10 - c;              // control bit position
                const int st = 10 - ((c + 1) % 11); // target bit position
                for (int i = tid; i < DIM; i += 256) {
                    int jj = i ^ (((i >> sc) & 1) << st);
                    vr[nxt][i] = vr[cur][jj];
                    vi[nxt][i] = vi[cur][jj];
                }
                __syncthreads();
                cur = nxt;
            }
        }
    }
    for (int i = tid; i < DIM; i += 256) {
        ut_re[(size_t)col*DIM + i] = f2bf(vr[cur][i]);
        ut_im[(size_t)col*DIM + i] = f2bf(vi[cur][i]);
    }
}

// ---------------------------------------------------------------------------
// Stage 1 (fp32 VALU): S = X * U^H. With T = U^T (T[a,b] = ut[a*DIM+b]):
//   S[i,n] = sum_k X[i,k]*conj(U[n,k]) = sum_k X[i,k]*(Tre[k,n] - i*Tim[k,n])
// 64x64 tile, BK=16, 256 threads, 4x4 micro-tile/thread. Explicit indices.
// ---------------------------------------------------------------------------
__global__ __launch_bounds__(256) void vgemm_s1(
        const float* __restrict__ x,
        const u16* __restrict__ tre, const u16* __restrict__ tim,
        u16* __restrict__ sre, u16* __restrict__ sim) {
    __shared__ alignas(16) float Xt[16][68];            // [k][i] (transposed)
    __shared__ alignas(16) float Br[16][68], Bi[16][68]; // [k][n]
    const int tid = threadIdx.x;
    const int r0 = blockIdx.y * 64, c0 = blockIdx.x * 64;
    const int tx = tid & 15, ty = tid >> 4;

    float accr[4][4] = {{0}}, acci[4][4] = {{0}};

    for (int k0 = 0; k0 < DIM; k0 += 16) {
        #pragma unroll
        for (int t = 0; t < 4; ++t) {
            int e = tid + t * 256;               // 1024 elements each tile
            int rr = e >> 4, kk = e & 15;
            Xt[kk][rr] = x[(size_t)(r0 + rr) * DIM + k0 + kk];
            int kk2 = e >> 6, cc = e & 63;
            Br[kk2][cc] = bf2f(tre[(size_t)(k0 + kk2) * DIM + c0 + cc]);
            Bi[kk2][cc] = bf2f(tim[(size_t)(k0 + kk2) * DIM + c0 + cc]);
        }
        __syncthreads();
        #pragma unroll
        for (int kk = 0; kk < 16; ++kk) {
            float4 a4 = *(const float4*)&Xt[kk][ty * 4];
            float4 br4 = *(const float4*)&Br[kk][tx * 4];
            float4 bi4 = *(const float4*)&Bi[kk][tx * 4];
            float a[4]  = {a4.x, a4.y, a4.z, a4.w};
            float br[4] = {br4.x, br4.y, br4.z, br4.w};
            float bi[4] = {bi4.x, bi4.y, bi4.z, bi4.w};
            #pragma unroll
            for (int i = 0; i < 4; ++i)
                #pragma unroll
                for (int j = 0; j < 4; ++j) {
                    accr[i][j] += a[i] * br[j];
                    acci[i][j] -= a[i] * bi[j];
                }
        }
        __syncthreads();
    }
    #pragma unroll
    for (int i = 0; i < 4; ++i)
        #pragma unroll
        for (int j = 0; j < 4; ++j) {
            size_t o = (size_t)(r0 + ty * 4 + i) * DIM + c0 + tx * 4 + j;
            sre[o] = f2bf(accr[i][j]);
            sim[o] = f2bf(acci[i][j]);
        }
}

// ---------------------------------------------------------------------------
// Stage 2 (fp32 VALU): out = U * S. U[m,k] = T[k,m]:
//   out[m,j] = sum_k (Tre[k,m] + i*Tim[k,m]) * (Sre[k,j] + i*Sim[k,j])
// mode 0: interleaved complex64 (float2), clamped to out_lim slots.
// mode 1: real part only, contiguous float (out_size == DIM*DIM case).
// ---------------------------------------------------------------------------
__global__ __launch_bounds__(256) void vgemm_s2(
        const u16* __restrict__ tre, const u16* __restrict__ tim,
        const u16* __restrict__ sre, const u16* __restrict__ sim,
        float* __restrict__ out, size_t out_lim, int mode) {
    __shared__ alignas(16) float Ar[16][68], Ai[16][68];  // [k][m]
    __shared__ alignas(16) float Br[16][68], Bi[16][68];  // [k][j]
    const int tid = threadIdx.x;
    const int r0 = blockIdx.y * 64, c0 = blockIdx.x * 64;
    const int tx = tid & 15, ty = tid >> 4;

    float accr[4][4] = {{0}}, acci[4][4] = {{0}};

    for (int k0 = 0; k0 < DIM; k0 += 16) {
        #pragma unroll
        for (int t = 0; t < 4; ++t) {
            int e = tid + t * 256;
            int kk = e >> 6, cc = e & 63;
            Ar[kk][cc] = bf2f(tre[(size_t)(k0 + kk) * DIM + r0 + cc]);
            Ai[kk][cc] = bf2f(tim[(size_t)(k0 + kk) * DIM + r0 + cc]);
            Br[kk][cc] = bf2f(sre[(size_t)(k0 + kk) * DIM + c0 + cc]);
            Bi[kk][cc] = bf2f(sim[(size_t)(k0 + kk) * DIM + c0 + cc]);
        }
        __syncthreads();
        #pragma unroll
        for (int kk = 0; kk < 16; ++kk) {
            float4 ar4 = *(const float4*)&Ar[kk][ty * 4];
            float4 ai4 = *(const float4*)&Ai[kk][ty * 4];
            float4 br4 = *(const float4*)&Br[kk][tx * 4];
            float4 bi4 = *(const float4*)&Bi[kk][tx * 4];
            float ar[4] = {ar4.x, ar4.y, ar4.z, ar4.w};
            float ai[4] = {ai4.x, ai4.y, ai4.z, ai4.w};
            float br[4] = {br4.x, br4.y, br4.z, br4.w};
            float bi[4] = {bi4.x, bi4.y, bi4.z, bi4.w};
            #pragma unroll
            for (int i = 0; i < 4; ++i)
                #pragma unroll
                for (int j = 0; j < 4; ++j) {
                    accr[i][j] += ar[i] * br[j] - ai[i] * bi[j];
                    acci[i][j] += ar[i] * bi[j] + ai[i] * br[j];
                }
        }
        __syncthreads();
    }
    #pragma unroll
    for (int i = 0; i < 4; ++i)
        #pragma unroll
        for (int j = 0; j < 4; ++j) {
            size_t idx = (size_t)(r0 + ty * 4 + i) * DIM + c0 + tx * 4 + j;
            if (mode == 0) {
                if (idx < out_lim)
                    ((float2*)out)[idx] = make_float2(accr[i][j], acci[i][j]);
            } else {
                out[idx] = accr[i][j];
            }
        }
}

// ---------------------------------------------------------------------------
// Workspace (32 MiB, bf16 planes): [0,8M) ut_re ; [8M,16M) ut_im ;
// [16M,24M) S_re ; [24M,32M) S_im.
// ---------------------------------------------------------------------------
extern "C" void kernel_launch(void* const* d_in, const int* in_sizes, int n_in,
                              void* d_out, int out_size, void* d_ws, size_t ws_size,
                              hipStream_t stream) {
    int xi = (in_sizes[0] >= in_sizes[1]) ? 0 : 1;
    const float* x = (const float*)d_in[xi];
    const float* w = (const float*)d_in[1 - xi];

    char* ws = (char*)d_ws;
    const size_t P = (size_t)DIM * DIM * 2;   // one bf16 plane = 8 MiB
    if (ws_size < 4 * P) return;              // diagnostic no-op if ws too small

    u16* ut_re = (u16*)(ws);
    u16* ut_im = (u16*)(ws + P);
    u16* s_re  = (u16*)(ws + 2*P);
    u16* s_im  = (u16*)(ws + 3*P);

    // Output-format hedge: out_size == DIM*DIM -> harness coerced complex to
    // float32 (real part, contiguous); otherwise interleaved complex64 pairs.
    int mode = (out_size == DIM * DIM) ? 1 : 0;
    size_t out_lim = (size_t)out_size / 2;    // float2 slots (mode 0)

    build_ut<<<DIM, 256, 0, stream>>>(w, ut_re, ut_im);
    vgemm_s1<<<dim3(32, 32), 256, 0, stream>>>(x, ut_re, ut_im, s_re, s_im);
    vgemm_s2<<<dim3(32, 32), 256, 0, stream>>>(ut_re, ut_im, s_re, s_im,
                                               (float*)d_out, out_lim, mode);
}

// Round 5
// 401.147 us; speedup vs baseline: 11.7924x; 11.7924x over previous
//
#include <hip/hip_runtime.h>

typedef unsigned short u16;
typedef __attribute__((ext_vector_type(8))) short bf16x8;   // 8 bf16 in 4 VGPRs
typedef __attribute__((ext_vector_type(4))) float f32x4;
typedef __attribute__((ext_vector_type(4))) unsigned int u32x4;

#define DIM 2048

__device__ inline u16 f2bf(float f) {
    unsigned u = __builtin_bit_cast(unsigned, f);
    u = (u + 0x7FFFu + ((u >> 16) & 1u)) >> 16;   // RNE, finite inputs only
    return (u16)u;
}

__device__ inline void gl_lds16(const void* g, void* l) {
    __builtin_amdgcn_global_load_lds(
        (const __attribute__((address_space(1))) unsigned int*)g,
        (__attribute__((address_space(3))) unsigned int*)l, 16, 0, 0);
}

struct c32 { float x, y; };
__device__ inline c32 cmul(c32 a, c32 b) { return {a.x*b.x - a.y*b.y, a.x*b.y + a.y*b.x}; }

// ---------------------------------------------------------------------------
// Kernel 1: build T = U^T (row j = column j of U) by per-column statevector
// simulation in LDS. Validated in round 4 (sequential ring permutations).
// ---------------------------------------------------------------------------
__global__ __launch_bounds__(256) void build_ut(const float* __restrict__ w,
                                                u16* __restrict__ ut_re,
                                                u16* __restrict__ ut_im) {
    __shared__ alignas(16) float gre[55][4], gim[55][4];
    __shared__ alignas(16) float vr[2][DIM], vi[2][DIM];
    const int tid = threadIdx.x;
    const int col = blockIdx.x;

    if (tid < 55) {
        const int layer = tid / 11, q = tid - layer * 11;
        const float WM = 0.63245553203367586f;   // sqrt(2)*5^-0.5
        float hx = 0.5f * WM * w[33*layer + q];
        float hy = 0.5f * WM * w[33*layer + 11 + q];
        float hz = 0.5f * WM * w[33*layer + 22 + q];
        float cx = cosf(hx), sx = sinf(hx);
        float cy = cosf(hy), sy = sinf(hy);
        float cz = cosf(hz), sz = sinf(hz);
        // Ry*Rx
        c32 m00{cy*cx,  sy*sx}, m01{-sy*cx, -cy*sx};
        c32 m10{sy*cx, -cy*sx}, m11{ cy*cx, -sy*sx};
        c32 em{cz, -sz}, ep{cz, sz};             // e^{-i hz}, e^{+i hz}
        c32 r0 = cmul(em, m00), r1 = cmul(em, m01);
        c32 r2 = cmul(ep, m10), r3 = cmul(ep, m11);
        gre[tid][0] = r0.x; gim[tid][0] = r0.y;
        gre[tid][1] = r1.x; gim[tid][1] = r1.y;
        gre[tid][2] = r2.x; gim[tid][2] = r2.y;
        gre[tid][3] = r3.x; gim[tid][3] = r3.y;
    }
    for (int i = tid; i < DIM; i += 256) { vr[0][i] = (i == col) ? 1.0f : 0.0f; vi[0][i] = 0.0f; }
    __syncthreads();

    int cur = 0;
    for (int layer = 0; layer < 5; ++layer) {
        for (int q = 0; q < 11; ++q) {
            const int gi = layer*11 + q;
            const float g00r = gre[gi][0], g00i = gim[gi][0];
            const float g01r = gre[gi][1], g01i = gim[gi][1];
            const float g10r = gre[gi][2], g10i = gim[gi][2];
            const float g11r = gre[gi][3], g11i = gim[gi][3];
            const int s = 10 - q;   // MSB-first: qubit q -> bit (n-1-q)
            for (int p = tid; p < 1024; p += 256) {
                int i0 = ((p >> s) << (s + 1)) | (p & ((1 << s) - 1));
                int i1 = i0 | (1 << s);
                float ar = vr[cur][i0], ai = vi[cur][i0];
                float br = vr[cur][i1], bi = vi[cur][i1];
                vr[cur][i0] = g00r*ar - g00i*ai + g01r*br - g01i*bi;
                vi[cur][i0] = g00r*ai + g00i*ar + g01r*bi + g01i*br;
                vr[cur][i1] = g10r*ar - g10i*ai + g11r*br - g11i*bi;
                vi[cur][i1] = g10r*ai + g10i*ar + g11r*bi + g11i*br;
            }
            __syncthreads();
        }
        if (layer < 4) {
            // U = U[p_c] sequentially, c = 0..10 (reference order).
            for (int c = 0; c < 11; ++c) {
                const int nxt = cur ^ 1;
                const int sc = 10 - c;              // control bit position
                const int st = 10 - ((c + 1) % 11); // target bit position
                for (int i = tid; i < DIM; i += 256) {
                    int jj = i ^ (((i >> sc) & 1) << st);
                    vr[nxt][i] = vr[cur][jj];
                    vi[nxt][i] = vi[cur][jj];
                }
                __syncthreads();
                cur = nxt;
            }
        }
    }
    for (int i = tid; i < DIM; i += 256) {
        ut_re[(size_t)col*DIM + i] = f2bf(vr[cur][i]);
        ut_im[(size_t)col*DIM + i] = f2bf(vi[cur][i]);
    }
}

// ---------------------------------------------------------------------------
// Kernel 2: bf16 transpose (U^T -> U), 64x64 LDS tiles; z selects re/im.
// ---------------------------------------------------------------------------
__global__ __launch_bounds__(256) void transpose2(const u16* __restrict__ sre,
                                                  const u16* __restrict__ sim,
                                                  u16* __restrict__ dre,
                                                  u16* __restrict__ dim_) {
    const u16* s = blockIdx.z ? sim : sre;
    u16*       d = blockIdx.z ? dim_ : dre;
    __shared__ alignas(16) u16 tile[64][66];
    const int bx = blockIdx.x * 64, by = blockIdx.y * 64;
    for (int e = threadIdx.x; e < 1024; e += 256) {
        int r = e >> 4, c4 = (e & 15) * 4;
        uint2 v = *(const uint2*)(s + (size_t)(by + r) * DIM + bx + c4);
        u16* tp = &tile[r][c4];
        tp[0] = (u16)(v.x); tp[1] = (u16)(v.x >> 16);
        tp[2] = (u16)(v.y); tp[3] = (u16)(v.y >> 16);
    }
    __syncthreads();
    for (int e = threadIdx.x; e < 1024; e += 256) {
        int r = e >> 4, c4 = (e & 15) * 4;
        unsigned lo = (unsigned)tile[c4][r]     | ((unsigned)tile[c4+1][r] << 16);
        unsigned hi = (unsigned)tile[c4+2][r]   | ((unsigned)tile[c4+3][r] << 16);
        *(uint2*)(d + (size_t)(bx + r) * DIM + by + c4) = make_uint2(lo, hi);
    }
}

// ---------------------------------------------------------------------------
// GEMM stage 1 (MFMA, fused): pt[m,n] = sum_k Ure[m,k] X[n,k]; qt with Uim.
// X read fp32 -> bf16 during LDS staging. 128x128 tile, BK=32, 4 waves.
// ---------------------------------------------------------------------------
__global__ __launch_bounds__(256, 1) void gemm_stage1(
        const u16* __restrict__ ure, const u16* __restrict__ uim,
        const float* __restrict__ x,
        u16* __restrict__ pt, u16* __restrict__ qt) {
    __shared__ alignas(16) u16 Ar[128*32], Ai[128*32], Bx[128*32];
    const int tid  = threadIdx.x;
    const int lane = tid & 63, w = tid >> 6;
    const int m0 = blockIdx.y * 128, n0 = blockIdx.x * 128;
    const int wm = (w >> 1) * 64, wn = (w & 1) * 64;
    const int ml = lane & 15, quad = lane >> 4;

    f32x4 accP[4][4], accQ[4][4];
    #pragma unroll
    for (int i = 0; i < 4; ++i)
        #pragma unroll
        for (int j = 0; j < 4; ++j) {
            f32x4 z = {0.f, 0.f, 0.f, 0.f};
            accP[i][j] = z; accQ[i][j] = z;
        }

    for (int k0 = 0; k0 < DIM; k0 += 32) {
        #pragma unroll
        for (int t = 0; t < 2; ++t) {
            int ci = t * 256 + tid;          // 16B chunk = 8 bf16
            int r = ci >> 2, c = ci & 3;
            size_t goA = ((size_t)(m0 + r) * DIM + k0) * 2 + c * 16;
            gl_lds16((const char*)ure + goA, (char*)Ar + ci * 16);
            gl_lds16((const char*)uim + goA, (char*)Ai + ci * 16);
            const float4* src = (const float4*)(x + (size_t)(n0 + r) * DIM + k0 + c * 8);
            float4 v0 = src[0], v1 = src[1];
            u32x4 pk;
            pk.x = (unsigned)f2bf(v0.x) | ((unsigned)f2bf(v0.y) << 16);
            pk.y = (unsigned)f2bf(v0.z) | ((unsigned)f2bf(v0.w) << 16);
            pk.z = (unsigned)f2bf(v1.x) | ((unsigned)f2bf(v1.y) << 16);
            pk.w = (unsigned)f2bf(v1.z) | ((unsigned)f2bf(v1.w) << 16);
            *(u32x4*)((char*)Bx + ci * 16) = pk;
        }
        __syncthreads();
        bf16x8 ar[4], ai[4], bx[4];
        #pragma unroll
        for (int i = 0; i < 4; ++i) {
            ar[i] = *(const bf16x8*)(Ar + (wm + i*16 + ml) * 32 + quad * 8);
            ai[i] = *(const bf16x8*)(Ai + (wm + i*16 + ml) * 32 + quad * 8);
            bx[i] = *(const bf16x8*)(Bx + (wn + i*16 + ml) * 32 + quad * 8);
        }
        #pragma unroll
        for (int i = 0; i < 4; ++i)
            #pragma unroll
            for (int j = 0; j < 4; ++j) {
                accP[i][j] = __builtin_amdgcn_mfma_f32_16x16x32_bf16(ar[i], bx[j], accP[i][j], 0, 0, 0);
                accQ[i][j] = __builtin_amdgcn_mfma_f32_16x16x32_bf16(ai[i], bx[j], accQ[i][j], 0, 0, 0);
            }
        __syncthreads();
    }
    // C/D layout: col = lane&15, row = quad*4 + reg
    #pragma unroll
    for (int i = 0; i < 4; ++i)
        #pragma unroll
        for (int j = 0; j < 4; ++j) {
            int row = m0 + wm + i*16 + quad*4;
            int col = n0 + wn + j*16 + ml;
            #pragma unroll
            for (int r = 0; r < 4; ++r) {
                pt[(size_t)(row + r) * DIM + col] = f2bf(accP[i][j][r]);
                qt[(size_t)(row + r) * DIM + col] = f2bf(accQ[i][j][r]);
            }
        }
}

// ---------------------------------------------------------------------------
// GEMM stage 2 (MFMA, real output only):
//   out[m,n] = sum_j Ure[m,j] pt[n,j] + Uim[m,j] qt[n,j]
//            = (Ure X Ure^T + Uim X Uim^T)[m,n] = Re(U X U^H)[m,n]
// Contiguous float32 stores (harness d_out = real part, DIM*DIM floats).
// ---------------------------------------------------------------------------
__global__ __launch_bounds__(256, 1) void gemm_stage2_real(
        const u16* __restrict__ ure, const u16* __restrict__ uim,
        const u16* __restrict__ pt, const u16* __restrict__ qt,
        float* __restrict__ out) {
    __shared__ alignas(16) u16 Ar[128*32], Ai[128*32], Bp[128*32], Bq[128*32];
    const int tid  = threadIdx.x;
    const int lane = tid & 63, w = tid >> 6;
    const int m0 = blockIdx.y * 128, n0 = blockIdx.x * 128;
    const int wm = (w >> 1) * 64, wn = (w & 1) * 64;
    const int ml = lane & 15, quad = lane >> 4;

    f32x4 accR[4][4];
    #pragma unroll
    for (int i = 0; i < 4; ++i)
        #pragma unroll
        for (int j = 0; j < 4; ++j) {
            f32x4 z = {0.f, 0.f, 0.f, 0.f};
            accR[i][j] = z;
        }

    for (int k0 = 0; k0 < DIM; k0 += 32) {
        #pragma unroll
        for (int t = 0; t < 2; ++t) {
            int ci = t * 256 + tid;
            int r = ci >> 2, c = ci & 3;
            size_t goA = ((size_t)(m0 + r) * DIM + k0) * 2 + c * 16;
            size_t goB = ((size_t)(n0 + r) * DIM + k0) * 2 + c * 16;
            gl_lds16((const char*)ure + goA, (char*)Ar + ci * 16);
            gl_lds16((const char*)uim + goA, (char*)Ai + ci * 16);
            gl_lds16((const char*)pt  + goB, (char*)Bp + ci * 16);
            gl_lds16((const char*)qt  + goB, (char*)Bq + ci * 16);
        }
        __syncthreads();
        bf16x8 ar[4], ai[4], bp[4], bq[4];
        #pragma unroll
        for (int i = 0; i < 4; ++i) {
            ar[i] = *(const bf16x8*)(Ar + (wm + i*16 + ml) * 32 + quad * 8);
            ai[i] = *(const bf16x8*)(Ai + (wm + i*16 + ml) * 32 + quad * 8);
            bp[i] = *(const bf16x8*)(Bp + (wn + i*16 + ml) * 32 + quad * 8);
            bq[i] = *(const bf16x8*)(Bq + (wn + i*16 + ml) * 32 + quad * 8);
        }
        #pragma unroll
        for (int i = 0; i < 4; ++i)
            #pragma unroll
            for (int j = 0; j < 4; ++j) {
                accR[i][j] = __builtin_amdgcn_mfma_f32_16x16x32_bf16(ar[i], bp[j], accR[i][j], 0, 0, 0);
                accR[i][j] = __builtin_amdgcn_mfma_f32_16x16x32_bf16(ai[i], bq[j], accR[i][j], 0, 0, 0);
            }
        __syncthreads();
    }
    #pragma unroll
    for (int i = 0; i < 4; ++i)
        #pragma unroll
        for (int j = 0; j < 4; ++j) {
            int row = m0 + wm + i*16 + quad*4;
            int col = n0 + wn + j*16 + ml;
            #pragma unroll
            for (int r = 0; r < 4; ++r)
                out[(size_t)(row + r) * DIM + col] = accR[i][j][r];
        }
}

// ---------------------------------------------------------------------------
// Fallback (mode 0, complex interleaved output) - not expected to run; kept
// as insurance against harness-format surprises.
// ---------------------------------------------------------------------------
__global__ __launch_bounds__(256, 1) void gemm_stage2_cplx(
        const u16* __restrict__ ure, const u16* __restrict__ uim,
        const u16* __restrict__ pt, const u16* __restrict__ qt,
        float2* __restrict__ out, size_t out_lim) {
    __shared__ alignas(16) u16 Ar[128*32], Ai[128*32], Bp[128*32], Bq[128*32];
    const int tid  = threadIdx.x;
    const int lane = tid & 63, w = tid >> 6;
    const int m0 = blockIdx.y * 128, n0 = blockIdx.x * 128;
    const int wm = (w >> 1) * 64, wn = (w & 1) * 64;
    const int ml = lane & 15, quad = lane >> 4;

    f32x4 accR[4][4], accI[4][4];
    #pragma unroll
    for (int i = 0; i < 4; ++i)
        #pragma unroll
        for (int j = 0; j < 4; ++j) {
            f32x4 z = {0.f, 0.f, 0.f, 0.f};
            accR[i][j] = z; accI[i][j] = z;
        }

    for (int k0 = 0; k0 < DIM; k0 += 32) {
        #pragma unroll
        for (int t = 0; t < 2; ++t) {
            int ci = t * 256 + tid;
            int r = ci >> 2, c = ci & 3;
            size_t goA = ((size_t)(m0 + r) * DIM + k0) * 2 + c * 16;
            size_t goB = ((size_t)(n0 + r) * DIM + k0) * 2 + c * 16;
            gl_lds16((const char*)ure + goA, (char*)Ar + ci * 16);
            gl_lds16((const char*)uim + goA, (char*)Ai + ci * 16);
            gl_lds16((const char*)pt  + goB, (char*)Bp + ci * 16);
            gl_lds16((const char*)qt  + goB, (char*)Bq + ci * 16);
        }
        __syncthreads();
        bf16x8 ar[4], ai[4], bp[4], bq[4];
        #pragma unroll
        for (int i = 0; i < 4; ++i) {
            ar[i] = *(const bf16x8*)(Ar + (wm + i*16 + ml) * 32 + quad * 8);
            ai[i] = *(const bf16x8*)(Ai + (wm + i*16 + ml) * 32 + quad * 8);
            bp[i] = *(const bf16x8*)(Bp + (wn + i*16 + ml) * 32 + quad * 8);
            bq[i] = *(const bf16x8*)(Bq + (wn + i*16 + ml) * 32 + quad * 8);
        }
        #pragma unroll
        for (int i = 0; i < 4; ++i)
            #pragma unroll
            for (int j = 0; j < 4; ++j) {
                accR[i][j] = __builtin_amdgcn_mfma_f32_16x16x32_bf16(ar[i], bp[j], accR[i][j], 0, 0, 0);
                accR[i][j] = __builtin_amdgcn_mfma_f32_16x16x32_bf16(ai[i], bq[j], accR[i][j], 0, 0, 0);
                accI[i][j] = __builtin_amdgcn_mfma_f32_16x16x32_bf16(ai[i], bp[j], accI[i][j], 0, 0, 0);
                f32x4 t2 = __builtin_amdgcn_mfma_f32_16x16x32_bf16(ar[i], bq[j], {0.f,0.f,0.f,0.f}, 0, 0, 0);
                accI[i][j] -= t2;
            }
        __syncthreads();
    }
    #pragma unroll
    for (int i = 0; i < 4; ++i)
        #pragma unroll
        for (int j = 0; j < 4; ++j) {
            int row = m0 + wm + i*16 + quad*4;
            int col = n0 + wn + j*16 + ml;
            #pragma unroll
            for (int r = 0; r < 4; ++r) {
                size_t idx = (size_t)(row + r) * DIM + col;
                if (idx < out_lim)
                    out[idx] = make_float2(accR[i][j][r], accI[i][j][r]);
            }
        }
}

// ---------------------------------------------------------------------------
// Workspace (32 MiB): [0,8M) ut_re->pt ; [8M,16M) ut_im->qt ; [16M,24M) u_re ;
// [24M,32M) u_im.
// ---------------------------------------------------------------------------
extern "C" void kernel_launch(void* const* d_in, const int* in_sizes, int n_in,
                              void* d_out, int out_size, void* d_ws, size_t ws_size,
                              hipStream_t stream) {
    int xi = (in_sizes[0] >= in_sizes[1]) ? 0 : 1;
    const float* x = (const float*)d_in[xi];
    const float* w = (const float*)d_in[1 - xi];

    char* ws = (char*)d_ws;
    const size_t P = (size_t)DIM * DIM * 2;   // one bf16 plane = 8 MiB
    if (ws_size < 4 * P) return;

    u16* ut_re = (u16*)(ws);
    u16* ut_im = (u16*)(ws + P);
    u16* u_re  = (u16*)(ws + 2*P);
    u16* u_im  = (u16*)(ws + 3*P);
    u16* pt    = ut_re;   // reuse after transpose
    u16* qt    = ut_im;

    build_ut<<<DIM, 256, 0, stream>>>(w, ut_re, ut_im);
    transpose2<<<dim3(32, 32, 2), 256, 0, stream>>>(ut_re, ut_im, u_re, u_im);
    gemm_stage1<<<dim3(16, 16), 256, 0, stream>>>(u_re, u_im, x, pt, qt);

    if (out_size == DIM * DIM) {
        gemm_stage2_real<<<dim3(16, 16), 256, 0, stream>>>(u_re, u_im, pt, qt,
                                                           (float*)d_out);
    } else {
        gemm_stage2_cplx<<<dim3(16, 16), 256, 0, stream>>>(u_re, u_im, pt, qt,
                                                           (float2*)d_out,
                                                           (size_t)out_size / 2);
    }
}

// Round 6
// 341.799 us; speedup vs baseline: 13.8399x; 1.1736x over previous
//
#include <hip/hip_runtime.h>

typedef unsigned short u16;
typedef __attribute__((ext_vector_type(8))) short bf16x8;   // 8 bf16 in 4 VGPRs
typedef __attribute__((ext_vector_type(4))) float f32x4;
typedef __attribute__((ext_vector_type(4))) unsigned int u32x4;

#define DIM 2048

__device__ inline u16 f2bf(float f) {
    unsigned u = __builtin_bit_cast(unsigned, f);
    u = (u + 0x7FFFu + ((u >> 16) & 1u)) >> 16;   // RNE, finite inputs only
    return (u16)u;
}

__device__ inline void gl_lds16(const void* g, void* l) {
    __builtin_amdgcn_global_load_lds(
        (const __attribute__((address_space(1))) unsigned int*)g,
        (__attribute__((address_space(3))) unsigned int*)l, 16, 0, 0);
}

struct c32 { float x, y; };
__device__ inline c32 cmul(c32 a, c32 b) { return {a.x*b.x - a.y*b.y, a.x*b.y + a.y*b.x}; }

// ---------------------------------------------------------------------------
// Kernel 1: build T = U^T, one column per block, statevector in LDS.
// Round-6 structure: 30 LDS passes/block (was 99):
//  - per layer: 5 fused 4x4 passes (qubit pairs (0,1)..(8,9)) + 1 2x2 pass (q=10)
//  - ring permutation composed into ptab (identical across layers; equals the
//    sequential p_0..p_10 of the PASSING round-4/5 kernel by construction) and
//    absorbed into the first fused pass of layers 1..4 via permuted reads
//    into the ping-pong buffer.
// ---------------------------------------------------------------------------
__global__ __launch_bounds__(256) void build_ut(const float* __restrict__ w,
                                                u16* __restrict__ ut_re,
                                                u16* __restrict__ ut_im) {
    __shared__ alignas(16) float gre[55][4], gim[55][4];     // 2x2 gates, row-major [i][j]
    __shared__ alignas(16) float G4r[5][5][16], G4i[5][5][16]; // fused 4x4 gates [layer][pair][v*4+v']
    __shared__ alignas(16) u16 ptab[DIM];                    // composed ring perm
    __shared__ alignas(16) float vr[2][DIM], vi[2][DIM];
    const int tid = threadIdx.x;
    const int col = blockIdx.x;

    // Phase 1: 2x2 fused XYZ gates (55 of them)
    if (tid < 55) {
        const int layer = tid / 11, q = tid - layer * 11;
        const float WM = 0.63245553203367586f;   // sqrt(2)*5^-0.5
        float hx = 0.5f * WM * w[33*layer + q];
        float hy = 0.5f * WM * w[33*layer + 11 + q];
        float hz = 0.5f * WM * w[33*layer + 22 + q];
        float cx = cosf(hx), sx = sinf(hx);
        float cy = cosf(hy), sy = sinf(hy);
        float cz = cosf(hz), sz = sinf(hz);
        // Ry*Rx
        c32 m00{cy*cx,  sy*sx}, m01{-sy*cx, -cy*sx};
        c32 m10{sy*cx, -cy*sx}, m11{ cy*cx, -sy*sx};
        c32 em{cz, -sz}, ep{cz, sz};             // e^{-i hz}, e^{+i hz}
        c32 r0 = cmul(em, m00), r1 = cmul(em, m01);
        c32 r2 = cmul(ep, m10), r3 = cmul(ep, m11);
        gre[tid][0] = r0.x; gim[tid][0] = r0.y;
        gre[tid][1] = r1.x; gim[tid][1] = r1.y;
        gre[tid][2] = r2.x; gim[tid][2] = r2.y;
        gre[tid][3] = r3.x; gim[tid][3] = r3.y;
    }
    // Init statevector + composed ring-perm table.
    // Sequential (PASSED in r4/r5): for c=0..10: v'[i] = v[p_c(i)].
    // Composed:  v_final[i] = v[p_0(p_1(...p_10(i)))]  -> apply c=10..0 to jj.
    for (int i = tid; i < DIM; i += 256) {
        vr[0][i] = (i == col) ? 1.0f : 0.0f; vi[0][i] = 0.0f;
        int jj = i;
        #pragma unroll
        for (int c = 10; c >= 0; --c) {
            int sc = 10 - c;
            int st = 10 - ((c + 1) % 11);
            jj ^= ((jj >> sc) & 1) << st;
        }
        ptab[i] = (u16)jj;
    }
    __syncthreads();

    // Phase 2: fused 4x4 gates G4 = g_{2p} (x) g_{2p+1}; entry (v,v') with
    // v = 2a+b (a = qubit 2p bit, b = qubit 2p+1 bit):
    //   G4[v][v'] = g_{2p}[a][a'] * g_{2p+1}[b][b']
    for (int t = tid; t < 400; t += 256) {
        int layer = t / 80, r = t % 80, pair = r / 16, e = r % 16;
        int v = e >> 2, vp = e & 3;
        int a = v >> 1, b = v & 1, ap = vp >> 1, bp = vp & 1;
        int gia = layer * 11 + 2 * pair, gib = gia + 1;
        c32 ga{gre[gia][a*2+ap], gim[gia][a*2+ap]};
        c32 gb{gre[gib][b*2+bp], gim[gib][b*2+bp]};
        c32 pr = cmul(ga, gb);
        G4r[layer][pair][e] = pr.x; G4i[layer][pair][e] = pr.y;
    }
    __syncthreads();

    int cur = 0;
    for (int layer = 0; layer < 5; ++layer) {
        // 5 fused pair passes: qubits (2p, 2p+1) -> bits (sa=10-2p, sb=sa-1)
        for (int pair = 0; pair < 5; ++pair) {
            const int sb = 9 - 2 * pair;       // lower bit of the pair
            float g4r[16], g4i[16];
            #pragma unroll
            for (int e = 0; e < 16; ++e) {
                g4r[e] = G4r[layer][pair][e];
                g4i[e] = G4i[layer][pair][e];
            }
            const bool permRead = (layer > 0) && (pair == 0);
            const int src = cur, dst = permRead ? (cur ^ 1) : cur;
            for (int g = tid; g < 512; g += 256) {
                int i0 = ((g >> sb) << (sb + 2)) | (g & ((1 << sb) - 1));
                float xr[4], xi[4];
                #pragma unroll
                for (int v = 0; v < 4; ++v) {
                    int idx = i0 | (v << sb);
                    int s2 = permRead ? (int)ptab[idx] : idx;
                    xr[v] = vr[src][s2]; xi[v] = vi[src][s2];
                }
                #pragma unroll
                for (int v = 0; v < 4; ++v) {
                    float sr = 0.f, si = 0.f;
                    #pragma unroll
                    for (int u = 0; u < 4; ++u) {
                        sr += g4r[v*4+u] * xr[u] - g4i[v*4+u] * xi[u];
                        si += g4r[v*4+u] * xi[u] + g4i[v*4+u] * xr[u];
                    }
                    vr[dst][i0 | (v << sb)] = sr;
                    vi[dst][i0 | (v << sb)] = si;
                }
            }
            __syncthreads();
            cur = dst;
        }
        // single qubit q=10, bit 0, in place
        {
            const int gi = layer * 11 + 10;
            const float g00r = gre[gi][0], g00i = gim[gi][0];
            const float g01r = gre[gi][1], g01i = gim[gi][1];
            const float g10r = gre[gi][2], g10i = gim[gi][2];
            const float g11r = gre[gi][3], g11i = gim[gi][3];
            for (int p = tid; p < 1024; p += 256) {
                int i0 = 2 * p, i1 = i0 + 1;
                float ar = vr[cur][i0], ai = vi[cur][i0];
                float br = vr[cur][i1], bi = vi[cur][i1];
                vr[cur][i0] = g00r*ar - g00i*ai + g01r*br - g01i*bi;
                vi[cur][i0] = g00r*ai + g00i*ar + g01r*bi + g01i*br;
                vr[cur][i1] = g10r*ar - g10i*ai + g11r*br - g11i*bi;
                vi[cur][i1] = g10r*ai + g10i*ar + g11r*bi + g11i*br;
            }
            __syncthreads();
        }
    }
    for (int i = tid; i < DIM; i += 256) {
        ut_re[(size_t)col*DIM + i] = f2bf(vr[cur][i]);
        ut_im[(size_t)col*DIM + i] = f2bf(vi[cur][i]);
    }
}

// ---------------------------------------------------------------------------
// Kernel 2: bf16 transpose (U^T -> U), 64x64 LDS tiles; z selects re/im.
// ---------------------------------------------------------------------------
__global__ __launch_bounds__(256) void transpose2(const u16* __restrict__ sre,
                                                  const u16* __restrict__ sim,
                                                  u16* __restrict__ dre,
                                                  u16* __restrict__ dim_) {
    const u16* s = blockIdx.z ? sim : sre;
    u16*       d = blockIdx.z ? dim_ : dre;
    __shared__ alignas(16) u16 tile[64][66];
    const int bx = blockIdx.x * 64, by = blockIdx.y * 64;
    for (int e = threadIdx.x; e < 1024; e += 256) {
        int r = e >> 4, c4 = (e & 15) * 4;
        uint2 v = *(const uint2*)(s + (size_t)(by + r) * DIM + bx + c4);
        u16* tp = &tile[r][c4];
        tp[0] = (u16)(v.x); tp[1] = (u16)(v.x >> 16);
        tp[2] = (u16)(v.y); tp[3] = (u16)(v.y >> 16);
    }
    __syncthreads();
    for (int e = threadIdx.x; e < 1024; e += 256) {
        int r = e >> 4, c4 = (e & 15) * 4;
        unsigned lo = (unsigned)tile[c4][r]     | ((unsigned)tile[c4+1][r] << 16);
        unsigned hi = (unsigned)tile[c4+2][r]   | ((unsigned)tile[c4+3][r] << 16);
        *(uint2*)(d + (size_t)(bx + r) * DIM + by + c4) = make_uint2(lo, hi);
    }
}

// ---------------------------------------------------------------------------
// GEMM stage 1 (MFMA, fused): pt[m,n] = sum_k Ure[m,k] X[n,k]; qt with Uim.
// ---------------------------------------------------------------------------
__global__ __launch_bounds__(256, 1) void gemm_stage1(
        const u16* __restrict__ ure, const u16* __restrict__ uim,
        const float* __restrict__ x,
        u16* __restrict__ pt, u16* __restrict__ qt) {
    __shared__ alignas(16) u16 Ar[128*32], Ai[128*32], Bx[128*32];
    const int tid  = threadIdx.x;
    const int lane = tid & 63, w = tid >> 6;
    const int m0 = blockIdx.y * 128, n0 = blockIdx.x * 128;
    const int wm = (w >> 1) * 64, wn = (w & 1) * 64;
    const int ml = lane & 15, quad = lane >> 4;

    f32x4 accP[4][4], accQ[4][4];
    #pragma unroll
    for (int i = 0; i < 4; ++i)
        #pragma unroll
        for (int j = 0; j < 4; ++j) {
            f32x4 z = {0.f, 0.f, 0.f, 0.f};
            accP[i][j] = z; accQ[i][j] = z;
        }

    for (int k0 = 0; k0 < DIM; k0 += 32) {
        #pragma unroll
        for (int t = 0; t < 2; ++t) {
            int ci = t * 256 + tid;          // 16B chunk = 8 bf16
            int r = ci >> 2, c = ci & 3;
            size_t goA = ((size_t)(m0 + r) * DIM + k0) * 2 + c * 16;
            gl_lds16((const char*)ure + goA, (char*)Ar + ci * 16);
            gl_lds16((const char*)uim + goA, (char*)Ai + ci * 16);
            const float4* src = (const float4*)(x + (size_t)(n0 + r) * DIM + k0 + c * 8);
            float4 v0 = src[0], v1 = src[1];
            u32x4 pk;
            pk.x = (unsigned)f2bf(v0.x) | ((unsigned)f2bf(v0.y) << 16);
            pk.y = (unsigned)f2bf(v0.z) | ((unsigned)f2bf(v0.w) << 16);
            pk.z = (unsigned)f2bf(v1.x) | ((unsigned)f2bf(v1.y) << 16);
            pk.w = (unsigned)f2bf(v1.z) | ((unsigned)f2bf(v1.w) << 16);
            *(u32x4*)((char*)Bx + ci * 16) = pk;
        }
        __syncthreads();
        bf16x8 ar[4], ai[4], bx[4];
        #pragma unroll
        for (int i = 0; i < 4; ++i) {
            ar[i] = *(const bf16x8*)(Ar + (wm + i*16 + ml) * 32 + quad * 8);
            ai[i] = *(const bf16x8*)(Ai + (wm + i*16 + ml) * 32 + quad * 8);
            bx[i] = *(const bf16x8*)(Bx + (wn + i*16 + ml) * 32 + quad * 8);
        }
        #pragma unroll
        for (int i = 0; i < 4; ++i)
            #pragma unroll
            for (int j = 0; j < 4; ++j) {
                accP[i][j] = __builtin_amdgcn_mfma_f32_16x16x32_bf16(ar[i], bx[j], accP[i][j], 0, 0, 0);
                accQ[i][j] = __builtin_amdgcn_mfma_f32_16x16x32_bf16(ai[i], bx[j], accQ[i][j], 0, 0, 0);
            }
        __syncthreads();
    }
    // C/D layout: col = lane&15, row = quad*4 + reg
    #pragma unroll
    for (int i = 0; i < 4; ++i)
        #pragma unroll
        for (int j = 0; j < 4; ++j) {
            int row = m0 + wm + i*16 + quad*4;
            int col = n0 + wn + j*16 + ml;
            #pragma unroll
            for (int r = 0; r < 4; ++r) {
                pt[(size_t)(row + r) * DIM + col] = f2bf(accP[i][j][r]);
                qt[(size_t)(row + r) * DIM + col] = f2bf(accQ[i][j][r]);
            }
        }
}

// ---------------------------------------------------------------------------
// GEMM stage 2 (MFMA, real output):
//   out[m,n] = sum_j Ure[m,j] pt[n,j] + Uim[m,j] qt[n,j] = Re(U X U^H)[m,n]
// ---------------------------------------------------------------------------
__global__ __launch_bounds__(256, 1) void gemm_stage2_real(
        const u16* __restrict__ ure, const u16* __restrict__ uim,
        const u16* __restrict__ pt, const u16* __restrict__ qt,
        float* __restrict__ out) {
    __shared__ alignas(16) u16 Ar[128*32], Ai[128*32], Bp[128*32], Bq[128*32];
    const int tid  = threadIdx.x;
    const int lane = tid & 63, w = tid >> 6;
    const int m0 = blockIdx.y * 128, n0 = blockIdx.x * 128;
    const int wm = (w >> 1) * 64, wn = (w & 1) * 64;
    const int ml = lane & 15, quad = lane >> 4;

    f32x4 accR[4][4];
    #pragma unroll
    for (int i = 0; i < 4; ++i)
        #pragma unroll
        for (int j = 0; j < 4; ++j) {
            f32x4 z = {0.f, 0.f, 0.f, 0.f};
            accR[i][j] = z;
        }

    for (int k0 = 0; k0 < DIM; k0 += 32) {
        #pragma unroll
        for (int t = 0; t < 2; ++t) {
            int ci = t * 256 + tid;
            int r = ci >> 2, c = ci & 3;
            size_t goA = ((size_t)(m0 + r) * DIM + k0) * 2 + c * 16;
            size_t goB = ((size_t)(n0 + r) * DIM + k0) * 2 + c * 16;
            gl_lds16((const char*)ure + goA, (char*)Ar + ci * 16);
            gl_lds16((const char*)uim + goA, (char*)Ai + ci * 16);
            gl_lds16((const char*)pt  + goB, (char*)Bp + ci * 16);
            gl_lds16((const char*)qt  + goB, (char*)Bq + ci * 16);
        }
        __syncthreads();
        bf16x8 ar[4], ai[4], bp[4], bq[4];
        #pragma unroll
        for (int i = 0; i < 4; ++i) {
            ar[i] = *(const bf16x8*)(Ar + (wm + i*16 + ml) * 32 + quad * 8);
            ai[i] = *(const bf16x8*)(Ai + (wm + i*16 + ml) * 32 + quad * 8);
            bp[i] = *(const bf16x8*)(Bp + (wn + i*16 + ml) * 32 + quad * 8);
            bq[i] = *(const bf16x8*)(Bq + (wn + i*16 + ml) * 32 + quad * 8);
        }
        #pragma unroll
        for (int i = 0; i < 4; ++i)
            #pragma unroll
            for (int j = 0; j < 4; ++j) {
                accR[i][j] = __builtin_amdgcn_mfma_f32_16x16x32_bf16(ar[i], bp[j], accR[i][j], 0, 0, 0);
                accR[i][j] = __builtin_amdgcn_mfma_f32_16x16x32_bf16(ai[i], bq[j], accR[i][j], 0, 0, 0);
            }
        __syncthreads();
    }
    #pragma unroll
    for (int i = 0; i < 4; ++i)
        #pragma unroll
        for (int j = 0; j < 4; ++j) {
            int row = m0 + wm + i*16 + quad*4;
            int col = n0 + wn + j*16 + ml;
            #pragma unroll
            for (int r = 0; r < 4; ++r)
                out[(size_t)(row + r) * DIM + col] = accR[i][j][r];
        }
}

// ---------------------------------------------------------------------------
// Fallback (complex interleaved output) — insurance only.
// ---------------------------------------------------------------------------
__global__ __launch_bounds__(256, 1) void gemm_stage2_cplx(
        const u16* __restrict__ ure, const u16* __restrict__ uim,
        const u16* __restrict__ pt, const u16* __restrict__ qt,
        float2* __restrict__ out, size_t out_lim) {
    __shared__ alignas(16) u16 Ar[128*32], Ai[128*32], Bp[128*32], Bq[128*32];
    const int tid  = threadIdx.x;
    const int lane = tid & 63, w = tid >> 6;
    const int m0 = blockIdx.y * 128, n0 = blockIdx.x * 128;
    const int wm = (w >> 1) * 64, wn = (w & 1) * 64;
    const int ml = lane & 15, quad = lane >> 4;

    f32x4 accR[4][4], accI[4][4];
    #pragma unroll
    for (int i = 0; i < 4; ++i)
        #pragma unroll
        for (int j = 0; j < 4; ++j) {
            f32x4 z = {0.f, 0.f, 0.f, 0.f};
            accR[i][j] = z; accI[i][j] = z;
        }

    for (int k0 = 0; k0 < DIM; k0 += 32) {
        #pragma unroll
        for (int t = 0; t < 2; ++t) {
            int ci = t * 256 + tid;
            int r = ci >> 2, c = ci & 3;
            size_t goA = ((size_t)(m0 + r) * DIM + k0) * 2 + c * 16;
            size_t goB = ((size_t)(n0 + r) * DIM + k0) * 2 + c * 16;
            gl_lds16((const char*)ure + goA, (char*)Ar + ci * 16);
            gl_lds16((const char*)uim + goA, (char*)Ai + ci * 16);
            gl_lds16((const char*)pt  + goB, (char*)Bp + ci * 16);
            gl_lds16((const char*)qt  + goB, (char*)Bq + ci * 16);
        }
        __syncthreads();
        bf16x8 ar[4], ai[4], bp[4], bq[4];
        #pragma unroll
        for (int i = 0; i < 4; ++i) {
            ar[i] = *(const bf16x8*)(Ar + (wm + i*16 + ml) * 32 + quad * 8);
            ai[i] = *(const bf16x8*)(Ai + (wm + i*16 + ml) * 32 + quad * 8);
            bp[i] = *(const bf16x8*)(Bp + (wn + i*16 + ml) * 32 + quad * 8);
            bq[i] = *(const bf16x8*)(Bq + (wn + i*16 + ml) * 32 + quad * 8);
        }
        #pragma unroll
        for (int i = 0; i < 4; ++i)
            #pragma unroll
            for (int j = 0; j < 4; ++j) {
                accR[i][j] = __builtin_amdgcn_mfma_f32_16x16x32_bf16(ar[i], bp[j], accR[i][j], 0, 0, 0);
                accR[i][j] = __builtin_amdgcn_mfma_f32_16x16x32_bf16(ai[i], bq[j], accR[i][j], 0, 0, 0);
                accI[i][j] = __builtin_amdgcn_mfma_f32_16x16x32_bf16(ai[i], bp[j], accI[i][j], 0, 0, 0);
                f32x4 t2 = __builtin_amdgcn_mfma_f32_16x16x32_bf16(ar[i], bq[j], {0.f,0.f,0.f,0.f}, 0, 0, 0);
                accI[i][j] -= t2;
            }
        __syncthreads();
    }
    #pragma unroll
    for (int i = 0; i < 4; ++i)
        #pragma unroll
        for (int j = 0; j < 4; ++j) {
            int row = m0 + wm + i*16 + quad*4;
            int col = n0 + wn + j*16 + ml;
            #pragma unroll
            for (int r = 0; r < 4; ++r) {
                size_t idx = (size_t)(row + r) * DIM + col;
                if (idx < out_lim)
                    out[idx] = make_float2(accR[i][j][r], accI[i][j][r]);
            }
        }
}

// ---------------------------------------------------------------------------
extern "C" void kernel_launch(void* const* d_in, const int* in_sizes, int n_in,
                              void* d_out, int out_size, void* d_ws, size_t ws_size,
                              hipStream_t stream) {
    int xi = (in_sizes[0] >= in_sizes[1]) ? 0 : 1;
    const float* x = (const float*)d_in[xi];
    const float* w = (const float*)d_in[1 - xi];

    char* ws = (char*)d_ws;
    const size_t P = (size_t)DIM * DIM * 2;   // one bf16 plane = 8 MiB
    if (ws_size < 4 * P) return;

    u16* ut_re = (u16*)(ws);
    u16* ut_im = (u16*)(ws + P);
    u16* u_re  = (u16*)(ws + 2*P);
    u16* u_im  = (u16*)(ws + 3*P);
    u16* pt    = ut_re;   // reuse after transpose
    u16* qt    = ut_im;

    build_ut<<<DIM, 256, 0, stream>>>(w, ut_re, ut_im);
    transpose2<<<dim3(32, 32, 2), 256, 0, stream>>>(ut_re, ut_im, u_re, u_im);
    gemm_stage1<<<dim3(16, 16), 256, 0, stream>>>(u_re, u_im, x, pt, qt);

    if (out_size == DIM * DIM) {
        gemm_stage2_real<<<dim3(16, 16), 256, 0, stream>>>(u_re, u_im, pt, qt,
                                                           (float*)d_out);
    } else {
        gemm_stage2_cplx<<<dim3(16, 16), 256, 0, stream>>>(u_re, u_im, pt, qt,
                                                           (float2*)d_out,
                                                           (size_t)out_size / 2);
    }
}

// Round 7
// 321.003 us; speedup vs baseline: 14.7366x; 1.0648x over previous
//
#include <hip/hip_runtime.h>

typedef unsigned short u16;
typedef __attribute__((ext_vector_type(8))) short bf16x8;   // 8 bf16 in 4 VGPRs
typedef __attribute__((ext_vector_type(4))) float f32x4;
typedef __attribute__((ext_vector_type(4))) unsigned int u32x4;

#define DIM 2048

__device__ inline u16 f2bf(float f) {
    unsigned u = __builtin_bit_cast(unsigned, f);
    u = (u + 0x7FFFu + ((u >> 16) & 1u)) >> 16;   // RNE, finite inputs only
    return (u16)u;
}

__device__ inline void gl_lds16(const void* g, void* l) {
    __builtin_amdgcn_global_load_lds(
        (const __attribute__((address_space(1))) unsigned int*)g,
        (__attribute__((address_space(3))) unsigned int*)l, 16, 0, 0);
}

struct c32 { float x, y; };
__device__ inline c32 cmul(c32 a, c32 b) { return {a.x*b.x - a.y*b.y, a.x*b.y + a.y*b.x}; }

// ---------------------------------------------------------------------------
// Kernel 1: build T = U^T, one column per block, statevector in LDS.
// 30 LDS passes/block: 5 fused 4x4 passes + 1 2x2 pass per layer; ring
// permutation composed into ptab and absorbed into the first fused pass of
// layers 1..4. Validated round 6.
// ---------------------------------------------------------------------------
__global__ __launch_bounds__(256) void build_ut(const float* __restrict__ w,
                                                u16* __restrict__ ut_re,
                                                u16* __restrict__ ut_im) {
    __shared__ alignas(16) float gre[55][4], gim[55][4];
    __shared__ alignas(16) float G4r[5][5][16], G4i[5][5][16];
    __shared__ alignas(16) u16 ptab[DIM];
    __shared__ alignas(16) float vr[2][DIM], vi[2][DIM];
    const int tid = threadIdx.x;
    const int col = blockIdx.x;

    if (tid < 55) {
        const int layer = tid / 11, q = tid - layer * 11;
        const float WM = 0.63245553203367586f;   // sqrt(2)*5^-0.5
        float hx = 0.5f * WM * w[33*layer + q];
        float hy = 0.5f * WM * w[33*layer + 11 + q];
        float hz = 0.5f * WM * w[33*layer + 22 + q];
        float cx = cosf(hx), sx = sinf(hx);
        float cy = cosf(hy), sy = sinf(hy);
        float cz = cosf(hz), sz = sinf(hz);
        c32 m00{cy*cx,  sy*sx}, m01{-sy*cx, -cy*sx};
        c32 m10{sy*cx, -cy*sx}, m11{ cy*cx, -sy*sx};
        c32 em{cz, -sz}, ep{cz, sz};
        c32 r0 = cmul(em, m00), r1 = cmul(em, m01);
        c32 r2 = cmul(ep, m10), r3 = cmul(ep, m11);
        gre[tid][0] = r0.x; gim[tid][0] = r0.y;
        gre[tid][1] = r1.x; gim[tid][1] = r1.y;
        gre[tid][2] = r2.x; gim[tid][2] = r2.y;
        gre[tid][3] = r3.x; gim[tid][3] = r3.y;
    }
    for (int i = tid; i < DIM; i += 256) {
        vr[0][i] = (i == col) ? 1.0f : 0.0f; vi[0][i] = 0.0f;
        int jj = i;
        #pragma unroll
        for (int c = 10; c >= 0; --c) {
            int sc = 10 - c;
            int st = 10 - ((c + 1) % 11);
            jj ^= ((jj >> sc) & 1) << st;
        }
        ptab[i] = (u16)jj;
    }
    __syncthreads();

    for (int t = tid; t < 400; t += 256) {
        int layer = t / 80, r = t % 80, pair = r / 16, e = r % 16;
        int v = e >> 2, vp = e & 3;
        int a = v >> 1, b = v & 1, ap = vp >> 1, bp = vp & 1;
        int gia = layer * 11 + 2 * pair, gib = gia + 1;
        c32 ga{gre[gia][a*2+ap], gim[gia][a*2+ap]};
        c32 gb{gre[gib][b*2+bp], gim[gib][b*2+bp]};
        c32 pr = cmul(ga, gb);
        G4r[layer][pair][e] = pr.x; G4i[layer][pair][e] = pr.y;
    }
    __syncthreads();

    int cur = 0;
    for (int layer = 0; layer < 5; ++layer) {
        for (int pair = 0; pair < 5; ++pair) {
            const int sb = 9 - 2 * pair;
            float g4r[16], g4i[16];
            #pragma unroll
            for (int e = 0; e < 16; ++e) {
                g4r[e] = G4r[layer][pair][e];
                g4i[e] = G4i[layer][pair][e];
            }
            const bool permRead = (layer > 0) && (pair == 0);
            const int src = cur, dst = permRead ? (cur ^ 1) : cur;
            for (int g = tid; g < 512; g += 256) {
                int i0 = ((g >> sb) << (sb + 2)) | (g & ((1 << sb) - 1));
                float xr[4], xi[4];
                #pragma unroll
                for (int v = 0; v < 4; ++v) {
                    int idx = i0 | (v << sb);
                    int s2 = permRead ? (int)ptab[idx] : idx;
                    xr[v] = vr[src][s2]; xi[v] = vi[src][s2];
                }
                #pragma unroll
                for (int v = 0; v < 4; ++v) {
                    float sr = 0.f, si = 0.f;
                    #pragma unroll
                    for (int u = 0; u < 4; ++u) {
                        sr += g4r[v*4+u] * xr[u] - g4i[v*4+u] * xi[u];
                        si += g4r[v*4+u] * xi[u] + g4i[v*4+u] * xr[u];
                    }
                    vr[dst][i0 | (v << sb)] = sr;
                    vi[dst][i0 | (v << sb)] = si;
                }
            }
            __syncthreads();
            cur = dst;
        }
        {
            const int gi = layer * 11 + 10;
            const float g00r = gre[gi][0], g00i = gim[gi][0];
            const float g01r = gre[gi][1], g01i = gim[gi][1];
            const float g10r = gre[gi][2], g10i = gim[gi][2];
            const float g11r = gre[gi][3], g11i = gim[gi][3];
            for (int p = tid; p < 1024; p += 256) {
                int i0 = 2 * p, i1 = i0 + 1;
                float ar = vr[cur][i0], ai = vi[cur][i0];
                float br = vr[cur][i1], bi = vi[cur][i1];
                vr[cur][i0] = g00r*ar - g00i*ai + g01r*br - g01i*bi;
                vi[cur][i0] = g00r*ai + g00i*ar + g01r*bi + g01i*br;
                vr[cur][i1] = g10r*ar - g10i*ai + g11r*br - g11i*bi;
                vi[cur][i1] = g10r*ai + g10i*ar + g11r*bi + g11i*br;
            }
            __syncthreads();
        }
    }
    for (int i = tid; i < DIM; i += 256) {
        ut_re[(size_t)col*DIM + i] = f2bf(vr[cur][i]);
        ut_im[(size_t)col*DIM + i] = f2bf(vi[cur][i]);
    }
}

// ---------------------------------------------------------------------------
// Kernel 2: bf16 transpose (U^T -> U), 64x64 LDS tiles; z selects re/im.
// ---------------------------------------------------------------------------
__global__ __launch_bounds__(256) void transpose2(const u16* __restrict__ sre,
                                                  const u16* __restrict__ sim,
                                                  u16* __restrict__ dre,
                                                  u16* __restrict__ dim_) {
    const u16* s = blockIdx.z ? sim : sre;
    u16*       d = blockIdx.z ? dim_ : dre;
    __shared__ alignas(16) u16 tile[64][66];
    const int bx = blockIdx.x * 64, by = blockIdx.y * 64;
    for (int e = threadIdx.x; e < 1024; e += 256) {
        int r = e >> 4, c4 = (e & 15) * 4;
        uint2 v = *(const uint2*)(s + (size_t)(by + r) * DIM + bx + c4);
        u16* tp = &tile[r][c4];
        tp[0] = (u16)(v.x); tp[1] = (u16)(v.x >> 16);
        tp[2] = (u16)(v.y); tp[3] = (u16)(v.y >> 16);
    }
    __syncthreads();
    for (int e = threadIdx.x; e < 1024; e += 256) {
        int r = e >> 4, c4 = (e & 15) * 4;
        unsigned lo = (unsigned)tile[c4][r]     | ((unsigned)tile[c4+1][r] << 16);
        unsigned hi = (unsigned)tile[c4+2][r]   | ((unsigned)tile[c4+3][r] << 16);
        *(uint2*)(d + (size_t)(bx + r) * DIM + by + c4) = make_uint2(lo, hi);
    }
}

// ---------------------------------------------------------------------------
// GEMM stage 1 (MFMA, fused, DOUBLE-BUFFERED): pt[m,n] = sum_k Ure[m,k] X[n,k];
// qt with Uim. X read fp32 -> bf16 during LDS staging. 1 block/CU => prefetch
// tile k+1 before the MFMA phase so the vmcnt(0) drain at the barrier is ~free.
// ---------------------------------------------------------------------------
__global__ __launch_bounds__(256, 1) void gemm_stage1(
        const u16* __restrict__ ure, const u16* __restrict__ uim,
        const float* __restrict__ x,
        u16* __restrict__ pt, u16* __restrict__ qt) {
    __shared__ alignas(16) u16 Ar[2][128*32], Ai[2][128*32], Bx[2][128*32];
    const int tid  = threadIdx.x;
    const int lane = tid & 63, w = tid >> 6;
    const int m0 = blockIdx.y * 128, n0 = blockIdx.x * 128;
    const int wm = (w >> 1) * 64, wn = (w & 1) * 64;
    const int ml = lane & 15, quad = lane >> 4;

    f32x4 accP[4][4], accQ[4][4];
    #pragma unroll
    for (int i = 0; i < 4; ++i)
        #pragma unroll
        for (int j = 0; j < 4; ++j) {
            f32x4 z = {0.f, 0.f, 0.f, 0.f};
            accP[i][j] = z; accQ[i][j] = z;
        }

    auto stage = [&](int b, int k0) {
        #pragma unroll
        for (int t = 0; t < 2; ++t) {
            int ci = t * 256 + tid;          // 16B chunk = 8 bf16
            int r = ci >> 2, c = ci & 3;
            size_t goA = ((size_t)(m0 + r) * DIM + k0) * 2 + c * 16;
            gl_lds16((const char*)ure + goA, (char*)Ar[b] + ci * 16);
            gl_lds16((const char*)uim + goA, (char*)Ai[b] + ci * 16);
            const float4* src = (const float4*)(x + (size_t)(n0 + r) * DIM + k0 + c * 8);
            float4 v0 = src[0], v1 = src[1];
            u32x4 pk;
            pk.x = (unsigned)f2bf(v0.x) | ((unsigned)f2bf(v0.y) << 16);
            pk.y = (unsigned)f2bf(v0.z) | ((unsigned)f2bf(v0.w) << 16);
            pk.z = (unsigned)f2bf(v1.x) | ((unsigned)f2bf(v1.y) << 16);
            pk.w = (unsigned)f2bf(v1.z) | ((unsigned)f2bf(v1.w) << 16);
            *(u32x4*)((char*)Bx[b] + ci * 16) = pk;
        }
    };

    stage(0, 0);
    __syncthreads();

    for (int k0 = 0; k0 < DIM; k0 += 32) {
        const int cb = (k0 >> 5) & 1;
        if (k0 + 32 < DIM) stage(cb ^ 1, k0 + 32);   // prefetch next tile

        bf16x8 ar[4], ai[4], bx[4];
        #pragma unroll
        for (int i = 0; i < 4; ++i) {
            ar[i] = *(const bf16x8*)(Ar[cb] + (wm + i*16 + ml) * 32 + quad * 8);
            ai[i] = *(const bf16x8*)(Ai[cb] + (wm + i*16 + ml) * 32 + quad * 8);
            bx[i] = *(const bf16x8*)(Bx[cb] + (wn + i*16 + ml) * 32 + quad * 8);
        }
        #pragma unroll
        for (int i = 0; i < 4; ++i)
            #pragma unroll
            for (int j = 0; j < 4; ++j) {
                accP[i][j] = __builtin_amdgcn_mfma_f32_16x16x32_bf16(ar[i], bx[j], accP[i][j], 0, 0, 0);
                accQ[i][j] = __builtin_amdgcn_mfma_f32_16x16x32_bf16(ai[i], bx[j], accQ[i][j], 0, 0, 0);
            }
        __syncthreads();
    }
    // C/D layout: col = lane&15, row = quad*4 + reg
    #pragma unroll
    for (int i = 0; i < 4; ++i)
        #pragma unroll
        for (int j = 0; j < 4; ++j) {
            int row = m0 + wm + i*16 + quad*4;
            int col = n0 + wn + j*16 + ml;
            #pragma unroll
            for (int r = 0; r < 4; ++r) {
                pt[(size_t)(row + r) * DIM + col] = f2bf(accP[i][j][r]);
                qt[(size_t)(row + r) * DIM + col] = f2bf(accQ[i][j][r]);
            }
        }
}

// ---------------------------------------------------------------------------
// GEMM stage 2 (MFMA, real output, DOUBLE-BUFFERED):
//   out[m,n] = sum_j Ure[m,j] pt[n,j] + Uim[m,j] qt[n,j] = Re(U X U^H)[m,n]
// LDS: 2 x 4 planes x 8 KB = 64 KB.
// ---------------------------------------------------------------------------
__global__ __launch_bounds__(256, 1) void gemm_stage2_real(
        const u16* __restrict__ ure, const u16* __restrict__ uim,
        const u16* __restrict__ pt, const u16* __restrict__ qt,
        float* __restrict__ out) {
    __shared__ alignas(16) u16 Ar[2][128*32], Ai[2][128*32], Bp[2][128*32], Bq[2][128*32];
    const int tid  = threadIdx.x;
    const int lane = tid & 63, w = tid >> 6;
    const int m0 = blockIdx.y * 128, n0 = blockIdx.x * 128;
    const int wm = (w >> 1) * 64, wn = (w & 1) * 64;
    const int ml = lane & 15, quad = lane >> 4;

    f32x4 accR[4][4];
    #pragma unroll
    for (int i = 0; i < 4; ++i)
        #pragma unroll
        for (int j = 0; j < 4; ++j) {
            f32x4 z = {0.f, 0.f, 0.f, 0.f};
            accR[i][j] = z;
        }

    auto stage = [&](int b, int k0) {
        #pragma unroll
        for (int t = 0; t < 2; ++t) {
            int ci = t * 256 + tid;
            int r = ci >> 2, c = ci & 3;
            size_t goA = ((size_t)(m0 + r) * DIM + k0) * 2 + c * 16;
            size_t goB = ((size_t)(n0 + r) * DIM + k0) * 2 + c * 16;
            gl_lds16((const char*)ure + goA, (char*)Ar[b] + ci * 16);
            gl_lds16((const char*)uim + goA, (char*)Ai[b] + ci * 16);
            gl_lds16((const char*)pt  + goB, (char*)Bp[b] + ci * 16);
            gl_lds16((const char*)qt  + goB, (char*)Bq[b] + ci * 16);
        }
    };

    stage(0, 0);
    __syncthreads();

    for (int k0 = 0; k0 < DIM; k0 += 32) {
        const int cb = (k0 >> 5) & 1;
        if (k0 + 32 < DIM) stage(cb ^ 1, k0 + 32);   // prefetch next tile

        bf16x8 ar[4], ai[4], bp[4], bq[4];
        #pragma unroll
        for (int i = 0; i < 4; ++i) {
            ar[i] = *(const bf16x8*)(Ar[cb] + (wm + i*16 + ml) * 32 + quad * 8);
            ai[i] = *(const bf16x8*)(Ai[cb] + (wm + i*16 + ml) * 32 + quad * 8);
            bp[i] = *(const bf16x8*)(Bp[cb] + (wn + i*16 + ml) * 32 + quad * 8);
            bq[i] = *(const bf16x8*)(Bq[cb] + (wn + i*16 + ml) * 32 + quad * 8);
        }
        #pragma unroll
        for (int i = 0; i < 4; ++i)
            #pragma unroll
            for (int j = 0; j < 4; ++j) {
                accR[i][j] = __builtin_amdgcn_mfma_f32_16x16x32_bf16(ar[i], bp[j], accR[i][j], 0, 0, 0);
                accR[i][j] = __builtin_amdgcn_mfma_f32_16x16x32_bf16(ai[i], bq[j], accR[i][j], 0, 0, 0);
            }
        __syncthreads();
    }
    #pragma unroll
    for (int i = 0; i < 4; ++i)
        #pragma unroll
        for (int j = 0; j < 4; ++j) {
            int row = m0 + wm + i*16 + quad*4;
            int col = n0 + wn + j*16 + ml;
            #pragma unroll
            for (int r = 0; r < 4; ++r)
                out[(size_t)(row + r) * DIM + col] = accR[i][j][r];
        }
}

// ---------------------------------------------------------------------------
// Fallback (complex interleaved output) — insurance only, single-buffered.
// ---------------------------------------------------------------------------
__global__ __launch_bounds__(256, 1) void gemm_stage2_cplx(
        const u16* __restrict__ ure, const u16* __restrict__ uim,
        const u16* __restrict__ pt, const u16* __restrict__ qt,
        float2* __restrict__ out, size_t out_lim) {
    __shared__ alignas(16) u16 Ar[128*32], Ai[128*32], Bp[128*32], Bq[128*32];
    const int tid  = threadIdx.x;
    const int lane = tid & 63, w = tid >> 6;
    const int m0 = blockIdx.y * 128, n0 = blockIdx.x * 128;
    const int wm = (w >> 1) * 64, wn = (w & 1) * 64;
    const int ml = lane & 15, quad = lane >> 4;

    f32x4 accR[4][4], accI[4][4];
    #pragma unroll
    for (int i = 0; i < 4; ++i)
        #pragma unroll
        for (int j = 0; j < 4; ++j) {
            f32x4 z = {0.f, 0.f, 0.f, 0.f};
            accR[i][j] = z; accI[i][j] = z;
        }

    for (int k0 = 0; k0 < DIM; k0 += 32) {
        #pragma unroll
        for (int t = 0; t < 2; ++t) {
            int ci = t * 256 + tid;
            int r = ci >> 2, c = ci & 3;
            size_t goA = ((size_t)(m0 + r) * DIM + k0) * 2 + c * 16;
            size_t goB = ((size_t)(n0 + r) * DIM + k0) * 2 + c * 16;
            gl_lds16((const char*)ure + goA, (char*)Ar + ci * 16);
            gl_lds16((const char*)uim + goA, (char*)Ai + ci * 16);
            gl_lds16((const char*)pt  + goB, (char*)Bp + ci * 16);
            gl_lds16((const char*)qt  + goB, (char*)Bq + ci * 16);
        }
        __syncthreads();
        bf16x8 ar[4], ai[4], bp[4], bq[4];
        #pragma unroll
        for (int i = 0; i < 4; ++i) {
            ar[i] = *(const bf16x8*)(Ar + (wm + i*16 + ml) * 32 + quad * 8);
            ai[i] = *(const bf16x8*)(Ai + (wm + i*16 + ml) * 32 + quad * 8);
            bp[i] = *(const bf16x8*)(Bp + (wn + i*16 + ml) * 32 + quad * 8);
            bq[i] = *(const bf16x8*)(Bq + (wn + i*16 + ml) * 32 + quad * 8);
        }
        #pragma unroll
        for (int i = 0; i < 4; ++i)
            #pragma unroll
            for (int j = 0; j < 4; ++j) {
                accR[i][j] = __builtin_amdgcn_mfma_f32_16x16x32_bf16(ar[i], bp[j], accR[i][j], 0, 0, 0);
                accR[i][j] = __builtin_amdgcn_mfma_f32_16x16x32_bf16(ai[i], bq[j], accR[i][j], 0, 0, 0);
                accI[i][j] = __builtin_amdgcn_mfma_f32_16x16x32_bf16(ai[i], bp[j], accI[i][j], 0, 0, 0);
                f32x4 t2 = __builtin_amdgcn_mfma_f32_16x16x32_bf16(ar[i], bq[j], {0.f,0.f,0.f,0.f}, 0, 0, 0);
                accI[i][j] -= t2;
            }
        __syncthreads();
    }
    #pragma unroll
    for (int i = 0; i < 4; ++i)
        #pragma unroll
        for (int j = 0; j < 4; ++j) {
            int row = m0 + wm + i*16 + quad*4;
            int col = n0 + wn + j*16 + ml;
            #pragma unroll
            for (int r = 0; r < 4; ++r) {
                size_t idx = (size_t)(row + r) * DIM + col;
                if (idx < out_lim)
                    out[idx] = make_float2(accR[i][j][r], accI[i][j][r]);
            }
        }
}

// ---------------------------------------------------------------------------
extern "C" void kernel_launch(void* const* d_in, const int* in_sizes, int n_in,
                              void* d_out, int out_size, void* d_ws, size_t ws_size,
                              hipStream_t stream) {
    int xi = (in_sizes[0] >= in_sizes[1]) ? 0 : 1;
    const float* x = (const float*)d_in[xi];
    const float* w = (const float*)d_in[1 - xi];

    char* ws = (char*)d_ws;
    const size_t P = (size_t)DIM * DIM * 2;   // one bf16 plane = 8 MiB
    if (ws_size < 4 * P) return;

    u16* ut_re = (u16*)(ws);
    u16* ut_im = (u16*)(ws + P);
    u16* u_re  = (u16*)(ws + 2*P);
    u16* u_im  = (u16*)(ws + 3*P);
    u16* pt    = ut_re;   // reuse after transpose
    u16* qt    = ut_im;

    build_ut<<<DIM, 256, 0, stream>>>(w, ut_re, ut_im);
    transpose2<<<dim3(32, 32, 2), 256, 0, stream>>>(ut_re, ut_im, u_re, u_im);
    gemm_stage1<<<dim3(16, 16), 256, 0, stream>>>(u_re, u_im, x, pt, qt);

    if (out_size == DIM * DIM) {
        gemm_stage2_real<<<dim3(16, 16), 256, 0, stream>>>(u_re, u_im, pt, qt,
                                                           (float*)d_out);
    } else {
        gemm_stage2_cplx<<<dim3(16, 16), 256, 0, stream>>>(u_re, u_im, pt, qt,
                                                           (float2*)d_out,
                                                           (size_t)out_size / 2);
    }
}

// Round 8
// 304.942 us; speedup vs baseline: 15.5127x; 1.0527x over previous
//
#include <hip/hip_runtime.h>

typedef unsigned short u16;
typedef __attribute__((ext_vector_type(8))) short bf16x8;   // 8 bf16 in 4 VGPRs
typedef __attribute__((ext_vector_type(4))) float f32x4;
typedef __attribute__((ext_vector_type(4))) unsigned int u32x4;

#define DIM 2048

__device__ inline u16 f2bf(float f) {
    unsigned u = __builtin_bit_cast(unsigned, f);
    u = (u + 0x7FFFu + ((u >> 16) & 1u)) >> 16;   // RNE, finite inputs only
    return (u16)u;
}

__device__ inline void gl_lds16(const void* g, void* l) {
    __builtin_amdgcn_global_load_lds(
        (const __attribute__((address_space(1))) unsigned int*)g,
        (__attribute__((address_space(3))) unsigned int*)l, 16, 0, 0);
}

struct c32 { float x, y; };
__device__ inline c32 cmul(c32 a, c32 b) { return {a.x*b.x - a.y*b.y, a.x*b.y + a.y*b.x}; }

__device__ inline int slotf(int i) { return i + (i >> 5); }   // bank-pad layout

// ---------------------------------------------------------------------------
// Kernel 1: build T = U^T, one column per block, statevector in LDS.
// Round-8 structure:
//  - qubit pairing (p, p+6) -> bit pairs (10,4),(9,3),(8,2),(7,1),(6,0) + bit5
//    single: each pass zeroes at most ONE bank-index bit (was two -> 8-way).
//  - padded layout slot(i)=i+(i>>5) spreads remaining residues.
//  - single statevector buffer (16.5 KB): non-perm passes are thread-local
//    (read-set==write-set); perm-absorbed passes use register staging with a
//    read/write barrier. Ring perm composed into ptab (validated r6/r7).
// ---------------------------------------------------------------------------
__global__ __launch_bounds__(256) void build_ut(const float* __restrict__ w,
                                                u16* __restrict__ ut_re,
                                                u16* __restrict__ ut_im) {
    __shared__ alignas(16) float gre[55][4], gim[55][4];
    __shared__ alignas(16) float G4r[5][5][16], G4i[5][5][16];
    __shared__ alignas(16) u16 ptab[DIM];                 // slot(perm(e)), by e
    __shared__ alignas(16) float vr[DIM + (DIM >> 5)], vi[DIM + (DIM >> 5)];
    const int tid = threadIdx.x;
    const int col = blockIdx.x;

    if (tid < 55) {
        const int layer = tid / 11, q = tid - layer * 11;
        const float WM = 0.63245553203367586f;   // sqrt(2)*5^-0.5
        float hx = 0.5f * WM * w[33*layer + q];
        float hy = 0.5f * WM * w[33*layer + 11 + q];
        float hz = 0.5f * WM * w[33*layer + 22 + q];
        float cx = cosf(hx), sx = sinf(hx);
        float cy = cosf(hy), sy = sinf(hy);
        float cz = cosf(hz), sz = sinf(hz);
        c32 m00{cy*cx,  sy*sx}, m01{-sy*cx, -cy*sx};
        c32 m10{sy*cx, -cy*sx}, m11{ cy*cx, -sy*sx};
        c32 em{cz, -sz}, ep{cz, sz};
        c32 r0 = cmul(em, m00), r1 = cmul(em, m01);
        c32 r2 = cmul(ep, m10), r3 = cmul(ep, m11);
        gre[tid][0] = r0.x; gim[tid][0] = r0.y;
        gre[tid][1] = r1.x; gim[tid][1] = r1.y;
        gre[tid][2] = r2.x; gim[tid][2] = r2.y;
        gre[tid][3] = r3.x; gim[tid][3] = r3.y;
    }
    // Init statevector (padded slots) + composed ring perm (stored as slots).
    for (int i = tid; i < DIM; i += 256) {
        vr[slotf(i)] = (i == col) ? 1.0f : 0.0f;
        vi[slotf(i)] = 0.0f;
        int jj = i;
        #pragma unroll
        for (int c = 10; c >= 0; --c) {
            int sc = 10 - c;
            int st = 10 - ((c + 1) % 11);
            jj ^= ((jj >> sc) & 1) << st;
        }
        ptab[i] = (u16)slotf(jj);
    }
    __syncthreads();

    // Fused 4x4 gates: pair p couples qubit p (high bit 10-p) with qubit p+6
    // (low bit 4-p). v = 2a+b, a = high-bit value, b = low-bit value.
    for (int t = tid; t < 400; t += 256) {
        int layer = t / 80, r = t % 80, pair = r / 16, e = r % 16;
        int v = e >> 2, vp = e & 3;
        int a = v >> 1, b = v & 1, ap = vp >> 1, bp = vp & 1;
        int gia = layer * 11 + pair;        // qubit p  (bit 10-p)
        int gib = layer * 11 + 6 + pair;    // qubit p+6 (bit 4-p)
        c32 ga{gre[gia][a*2+ap], gim[gia][a*2+ap]};
        c32 gb{gre[gib][b*2+bp], gim[gib][b*2+bp]};
        c32 pr = cmul(ga, gb);
        G4r[layer][pair][e] = pr.x; G4i[layer][pair][e] = pr.y;
    }
    __syncthreads();

    for (int layer = 0; layer < 5; ++layer) {
        for (int p = 0; p < 5; ++p) {
            const int lo = 4 - p, hi = 10 - p;
            float g4r[16], g4i[16];
            #pragma unroll
            for (int e = 0; e < 16; ++e) {
                g4r[e] = G4r[layer][p][e];
                g4i[e] = G4i[layer][p][e];
            }
            const bool permRead = (layer > 0) && (p == 0);
            if (permRead) {
                // register staging: read ALL, barrier, write ALL
                float xr[2][4], xi[2][4];
                int es[2][4];
                #pragma unroll
                for (int h = 0; h < 2; ++h) {
                    int g = tid + h * 256;
                    int tmp = ((g >> lo) << (lo + 1)) | (g & ((1 << lo) - 1));
                    int i0  = ((tmp >> hi) << (hi + 1)) | (tmp & ((1 << hi) - 1));
                    #pragma unroll
                    for (int v = 0; v < 4; ++v) {
                        int e = i0 | ((v >> 1) << hi) | ((v & 1) << lo);
                        es[h][v] = slotf(e);
                        int ss = (int)ptab[e];
                        xr[h][v] = vr[ss]; xi[h][v] = vi[ss];
                    }
                }
                __syncthreads();
                #pragma unroll
                for (int h = 0; h < 2; ++h)
                    #pragma unroll
                    for (int v = 0; v < 4; ++v) {
                        float sr = 0.f, si = 0.f;
                        #pragma unroll
                        for (int u = 0; u < 4; ++u) {
                            sr += g4r[v*4+u] * xr[h][u] - g4i[v*4+u] * xi[h][u];
                            si += g4r[v*4+u] * xi[h][u] + g4i[v*4+u] * xr[h][u];
                        }
                        vr[es[h][v]] = sr; vi[es[h][v]] = si;
                    }
                __syncthreads();
            } else {
                // thread-local groups: read/compute/write, one end barrier
                #pragma unroll
                for (int h = 0; h < 2; ++h) {
                    int g = tid + h * 256;
                    int tmp = ((g >> lo) << (lo + 1)) | (g & ((1 << lo) - 1));
                    int i0  = ((tmp >> hi) << (hi + 1)) | (tmp & ((1 << hi) - 1));
                    float xr[4], xi[4];
                    int es[4];
                    #pragma unroll
                    for (int v = 0; v < 4; ++v) {
                        int e = i0 | ((v >> 1) << hi) | ((v & 1) << lo);
                        es[v] = slotf(e);
                        xr[v] = vr[es[v]]; xi[v] = vi[es[v]];
                    }
                    #pragma unroll
                    for (int v = 0; v < 4; ++v) {
                        float sr = 0.f, si = 0.f;
                        #pragma unroll
                        for (int u = 0; u < 4; ++u) {
                            sr += g4r[v*4+u] * xr[u] - g4i[v*4+u] * xi[u];
                            si += g4r[v*4+u] * xi[u] + g4i[v*4+u] * xr[u];
                        }
                        vr[es[v]] = sr; vi[es[v]] = si;
                    }
                }
                __syncthreads();
            }
        }
        // single qubit 5 (bit 5), in place, conflict-free (low5 untouched)
        {
            const int gi = layer * 11 + 5;
            const float g00r = gre[gi][0], g00i = gim[gi][0];
            const float g01r = gre[gi][1], g01i = gim[gi][1];
            const float g10r = gre[gi][2], g10i = gim[gi][2];
            const float g11r = gre[gi][3], g11i = gim[gi][3];
            #pragma unroll
            for (int t = 0; t < 4; ++t) {
                int p2 = tid + t * 256;
                int i0 = ((p2 >> 5) << 6) | (p2 & 31);
                int s0 = slotf(i0), s1 = slotf(i0 + 32);
                float ar = vr[s0], ai = vi[s0];
                float br = vr[s1], bi = vi[s1];
                vr[s0] = g00r*ar - g00i*ai + g01r*br - g01i*bi;
                vi[s0] = g00r*ai + g00i*ar + g01r*bi + g01i*br;
                vr[s1] = g10r*ar - g10i*ai + g11r*br - g11i*bi;
                vi[s1] = g10r*ai + g10i*ar + g11r*bi + g11i*br;
            }
            __syncthreads();
        }
    }
    for (int i = tid; i < DIM; i += 256) {
        ut_re[(size_t)col*DIM + i] = f2bf(vr[slotf(i)]);
        ut_im[(size_t)col*DIM + i] = f2bf(vi[slotf(i)]);
    }
}

// ---------------------------------------------------------------------------
// Kernel 2: bf16 transpose (U^T -> U), 64x64 LDS tiles; z selects re/im.
// ---------------------------------------------------------------------------
__global__ __launch_bounds__(256) void transpose2(const u16* __restrict__ sre,
                                                  const u16* __restrict__ sim,
                                                  u16* __restrict__ dre,
                                                  u16* __restrict__ dim_) {
    const u16* s = blockIdx.z ? sim : sre;
    u16*       d = blockIdx.z ? dim_ : dre;
    __shared__ alignas(16) u16 tile[64][66];
    const int bx = blockIdx.x * 64, by = blockIdx.y * 64;
    for (int e = threadIdx.x; e < 1024; e += 256) {
        int r = e >> 4, c4 = (e & 15) * 4;
        uint2 v = *(const uint2*)(s + (size_t)(by + r) * DIM + bx + c4);
        u16* tp = &tile[r][c4];
        tp[0] = (u16)(v.x); tp[1] = (u16)(v.x >> 16);
        tp[2] = (u16)(v.y); tp[3] = (u16)(v.y >> 16);
    }
    __syncthreads();
    for (int e = threadIdx.x; e < 1024; e += 256) {
        int r = e >> 4, c4 = (e & 15) * 4;
        unsigned lo = (unsigned)tile[c4][r]     | ((unsigned)tile[c4+1][r] << 16);
        unsigned hi = (unsigned)tile[c4+2][r]   | ((unsigned)tile[c4+3][r] << 16);
        *(uint2*)(d + (size_t)(bx + r) * DIM + by + c4) = make_uint2(lo, hi);
    }
}

// ---------------------------------------------------------------------------
// GEMM stage 1 (MFMA, fused, double-buffered): pt[m,n] = sum_k Ure[m,k] X[n,k];
// qt with Uim. X read fp32 -> bf16 during LDS staging.
// ---------------------------------------------------------------------------
__global__ __launch_bounds__(256, 1) void gemm_stage1(
        const u16* __restrict__ ure, const u16* __restrict__ uim,
        const float* __restrict__ x,
        u16* __restrict__ pt, u16* __restrict__ qt) {
    __shared__ alignas(16) u16 Ar[2][128*32], Ai[2][128*32], Bx[2][128*32];
    const int tid  = threadIdx.x;
    const int lane = tid & 63, w = tid >> 6;
    const int m0 = blockIdx.y * 128, n0 = blockIdx.x * 128;
    const int wm = (w >> 1) * 64, wn = (w & 1) * 64;
    const int ml = lane & 15, quad = lane >> 4;

    f32x4 accP[4][4], accQ[4][4];
    #pragma unroll
    for (int i = 0; i < 4; ++i)
        #pragma unroll
        for (int j = 0; j < 4; ++j) {
            f32x4 z = {0.f, 0.f, 0.f, 0.f};
            accP[i][j] = z; accQ[i][j] = z;
        }

    auto stage = [&](int b, int k0) {
        #pragma unroll
        for (int t = 0; t < 2; ++t) {
            int ci = t * 256 + tid;          // 16B chunk = 8 bf16
            int r = ci >> 2, c = ci & 3;
            size_t goA = ((size_t)(m0 + r) * DIM + k0) * 2 + c * 16;
            gl_lds16((const char*)ure + goA, (char*)Ar[b] + ci * 16);
            gl_lds16((const char*)uim + goA, (char*)Ai[b] + ci * 16);
            const float4* src = (const float4*)(x + (size_t)(n0 + r) * DIM + k0 + c * 8);
            float4 v0 = src[0], v1 = src[1];
            u32x4 pk;
            pk.x = (unsigned)f2bf(v0.x) | ((unsigned)f2bf(v0.y) << 16);
            pk.y = (unsigned)f2bf(v0.z) | ((unsigned)f2bf(v0.w) << 16);
            pk.z = (unsigned)f2bf(v1.x) | ((unsigned)f2bf(v1.y) << 16);
            pk.w = (unsigned)f2bf(v1.z) | ((unsigned)f2bf(v1.w) << 16);
            *(u32x4*)((char*)Bx[b] + ci * 16) = pk;
        }
    };

    stage(0, 0);
    __syncthreads();

    for (int k0 = 0; k0 < DIM; k0 += 32) {
        const int cb = (k0 >> 5) & 1;
        if (k0 + 32 < DIM) stage(cb ^ 1, k0 + 32);   // prefetch next tile

        bf16x8 ar[4], ai[4], bx[4];
        #pragma unroll
        for (int i = 0; i < 4; ++i) {
            ar[i] = *(const bf16x8*)(Ar[cb] + (wm + i*16 + ml) * 32 + quad * 8);
            ai[i] = *(const bf16x8*)(Ai[cb] + (wm + i*16 + ml) * 32 + quad * 8);
            bx[i] = *(const bf16x8*)(Bx[cb] + (wn + i*16 + ml) * 32 + quad * 8);
        }
        #pragma unroll
        for (int i = 0; i < 4; ++i)
            #pragma unroll
            for (int j = 0; j < 4; ++j) {
                accP[i][j] = __builtin_amdgcn_mfma_f32_16x16x32_bf16(ar[i], bx[j], accP[i][j], 0, 0, 0);
                accQ[i][j] = __builtin_amdgcn_mfma_f32_16x16x32_bf16(ai[i], bx[j], accQ[i][j], 0, 0, 0);
            }
        __syncthreads();
    }
    // C/D layout: col = lane&15, row = quad*4 + reg
    #pragma unroll
    for (int i = 0; i < 4; ++i)
        #pragma unroll
        for (int j = 0; j < 4; ++j) {
            int row = m0 + wm + i*16 + quad*4;
            int col = n0 + wn + j*16 + ml;
            #pragma unroll
            for (int r = 0; r < 4; ++r) {
                pt[(size_t)(row + r) * DIM + col] = f2bf(accP[i][j][r]);
                qt[(size_t)(row + r) * DIM + col] = f2bf(accQ[i][j][r]);
            }
        }
}

// ---------------------------------------------------------------------------
// GEMM stage 2 (MFMA, real output, double-buffered):
//   out[m,n] = sum_j Ure[m,j] pt[n,j] + Uim[m,j] qt[n,j] = Re(U X U^H)[m,n]
// ---------------------------------------------------------------------------
__global__ __launch_bounds__(256, 1) void gemm_stage2_real(
        const u16* __restrict__ ure, const u16* __restrict__ uim,
        const u16* __restrict__ pt, const u16* __restrict__ qt,
        float* __restrict__ out) {
    __shared__ alignas(16) u16 Ar[2][128*32], Ai[2][128*32], Bp[2][128*32], Bq[2][128*32];
    const int tid  = threadIdx.x;
    const int lane = tid & 63, w = tid >> 6;
    const int m0 = blockIdx.y * 128, n0 = blockIdx.x * 128;
    const int wm = (w >> 1) * 64, wn = (w & 1) * 64;
    const int ml = lane & 15, quad = lane >> 4;

    f32x4 accR[4][4];
    #pragma unroll
    for (int i = 0; i < 4; ++i)
        #pragma unroll
        for (int j = 0; j < 4; ++j) {
            f32x4 z = {0.f, 0.f, 0.f, 0.f};
            accR[i][j] = z;
        }

    auto stage = [&](int b, int k0) {
        #pragma unroll
        for (int t = 0; t < 2; ++t) {
            int ci = t * 256 + tid;
            int r = ci >> 2, c = ci & 3;
            size_t goA = ((size_t)(m0 + r) * DIM + k0) * 2 + c * 16;
            size_t goB = ((size_t)(n0 + r) * DIM + k0) * 2 + c * 16;
            gl_lds16((const char*)ure + goA, (char*)Ar[b] + ci * 16);
            gl_lds16((const char*)uim + goA, (char*)Ai[b] + ci * 16);
            gl_lds16((const char*)pt  + goB, (char*)Bp[b] + ci * 16);
            gl_lds16((const char*)qt  + goB, (char*)Bq[b] + ci * 16);
        }
    };

    stage(0, 0);
    __syncthreads();

    for (int k0 = 0; k0 < DIM; k0 += 32) {
        const int cb = (k0 >> 5) & 1;
        if (k0 + 32 < DIM) stage(cb ^ 1, k0 + 32);   // prefetch next tile

        bf16x8 ar[4], ai[4], bp[4], bq[4];
        #pragma unroll
        for (int i = 0; i < 4; ++i) {
            ar[i] = *(const bf16x8*)(Ar[cb] + (wm + i*16 + ml) * 32 + quad * 8);
            ai[i] = *(const bf16x8*)(Ai[cb] + (wm + i*16 + ml) * 32 + quad * 8);
            bp[i] = *(const bf16x8*)(Bp[cb] + (wn + i*16 + ml) * 32 + quad * 8);
            bq[i] = *(const bf16x8*)(Bq[cb] + (wn + i*16 + ml) * 32 + quad * 8);
        }
        #pragma unroll
        for (int i = 0; i < 4; ++i)
            #pragma unroll
            for (int j = 0; j < 4; ++j) {
                accR[i][j] = __builtin_amdgcn_mfma_f32_16x16x32_bf16(ar[i], bp[j], accR[i][j], 0, 0, 0);
                accR[i][j] = __builtin_amdgcn_mfma_f32_16x16x32_bf16(ai[i], bq[j], accR[i][j], 0, 0, 0);
            }
        __syncthreads();
    }
    #pragma unroll
    for (int i = 0; i < 4; ++i)
        #pragma unroll
        for (int j = 0; j < 4; ++j) {
            int row = m0 + wm + i*16 + quad*4;
            int col = n0 + wn + j*16 + ml;
            #pragma unroll
            for (int r = 0; r < 4; ++r)
                out[(size_t)(row + r) * DIM + col] = accR[i][j][r];
        }
}

// ---------------------------------------------------------------------------
// Fallback (complex interleaved output) — insurance only, single-buffered.
// ---------------------------------------------------------------------------
__global__ __launch_bounds__(256, 1) void gemm_stage2_cplx(
        const u16* __restrict__ ure, const u16* __restrict__ uim,
        const u16* __restrict__ pt, const u16* __restrict__ qt,
        float2* __restrict__ out, size_t out_lim) {
    __shared__ alignas(16) u16 Ar[128*32], Ai[128*32], Bp[128*32], Bq[128*32];
    const int tid  = threadIdx.x;
    const int lane = tid & 63, w = tid >> 6;
    const int m0 = blockIdx.y * 128, n0 = blockIdx.x * 128;
    const int wm = (w >> 1) * 64, wn = (w & 1) * 64;
    const int ml = lane & 15, quad = lane >> 4;

    f32x4 accR[4][4], accI[4][4];
    #pragma unroll
    for (int i = 0; i < 4; ++i)
        #pragma unroll
        for (int j = 0; j < 4; ++j) {
            f32x4 z = {0.f, 0.f, 0.f, 0.f};
            accR[i][j] = z; accI[i][j] = z;
        }

    for (int k0 = 0; k0 < DIM; k0 += 32) {
        #pragma unroll
        for (int t = 0; t < 2; ++t) {
            int ci = t * 256 + tid;
            int r = ci >> 2, c = ci & 3;
            size_t goA = ((size_t)(m0 + r) * DIM + k0) * 2 + c * 16;
            size_t goB = ((size_t)(n0 + r) * DIM + k0) * 2 + c * 16;
            gl_lds16((const char*)ure + goA, (char*)Ar + ci * 16);
            gl_lds16((const char*)uim + goA, (char*)Ai + ci * 16);
            gl_lds16((const char*)pt  + goB, (char*)Bp + ci * 16);
            gl_lds16((const char*)qt  + goB, (char*)Bq + ci * 16);
        }
        __syncthreads();
        bf16x8 ar[4], ai[4], bp[4], bq[4];
        #pragma unroll
        for (int i = 0; i < 4; ++i) {
            ar[i] = *(const bf16x8*)(Ar + (wm + i*16 + ml) * 32 + quad * 8);
            ai[i] = *(const bf16x8*)(Ai + (wm + i*16 + ml) * 32 + quad * 8);
            bp[i] = *(const bf16x8*)(Bp + (wn + i*16 + ml) * 32 + quad * 8);
            bq[i] = *(const bf16x8*)(Bq + (wn + i*16 + ml) * 32 + quad * 8);
        }
        #pragma unroll
        for (int i = 0; i < 4; ++i)
            #pragma unroll
            for (int j = 0; j < 4; ++j) {
                accR[i][j] = __builtin_amdgcn_mfma_f32_16x16x32_bf16(ar[i], bp[j], accR[i][j], 0, 0, 0);
                accR[i][j] = __builtin_amdgcn_mfma_f32_16x16x32_bf16(ai[i], bq[j], accR[i][j], 0, 0, 0);
                accI[i][j] = __builtin_amdgcn_mfma_f32_16x16x32_bf16(ai[i], bp[j], accI[i][j], 0, 0, 0);
                f32x4 t2 = __builtin_amdgcn_mfma_f32_16x16x32_bf16(ar[i], bq[j], {0.f,0.f,0.f,0.f}, 0, 0, 0);
                accI[i][j] -= t2;
            }
        __syncthreads();
    }
    #pragma unroll
    for (int i = 0; i < 4; ++i)
        #pragma unroll
        for (int j = 0; j < 4; ++j) {
            int row = m0 + wm + i*16 + quad*4;
            int col = n0 + wn + j*16 + ml;
            #pragma unroll
            for (int r = 0; r < 4; ++r) {
                size_t idx = (size_t)(row + r) * DIM + col;
                if (idx < out_lim)
                    out[idx] = make_float2(accR[i][j][r], accI[i][j][r]);
            }
        }
}

// ---------------------------------------------------------------------------
extern "C" void kernel_launch(void* const* d_in, const int* in_sizes, int n_in,
                              void* d_out, int out_size, void* d_ws, size_t ws_size,
                              hipStream_t stream) {
    int xi = (in_sizes[0] >= in_sizes[1]) ? 0 : 1;
    const float* x = (const float*)d_in[xi];
    const float* w = (const float*)d_in[1 - xi];

    char* ws = (char*)d_ws;
    const size_t P = (size_t)DIM * DIM * 2;   // one bf16 plane = 8 MiB
    if (ws_size < 4 * P) return;

    u16* ut_re = (u16*)(ws);
    u16* ut_im = (u16*)(ws + P);
    u16* u_re  = (u16*)(ws + 2*P);
    u16* u_im  = (u16*)(ws + 3*P);
    u16* pt    = ut_re;   // reuse after transpose
    u16* qt    = ut_im;

    build_ut<<<DIM, 256, 0, stream>>>(w, ut_re, ut_im);
    transpose2<<<dim3(32, 32, 2), 256, 0, stream>>>(ut_re, ut_im, u_re, u_im);
    gemm_stage1<<<dim3(16, 16), 256, 0, stream>>>(u_re, u_im, x, pt, qt);

    if (out_size == DIM * DIM) {
        gemm_stage2_real<<<dim3(16, 16), 256, 0, stream>>>(u_re, u_im, pt, qt,
                                                           (float*)d_out);
    } else {
        gemm_stage2_cplx<<<dim3(16, 16), 256, 0, stream>>>(u_re, u_im, pt, qt,
                                                           (float2*)d_out,
                                                           (size_t)out_size / 2);
    }
}